// Round 1
// baseline (1153.343 us; speedup 1.0000x reference)
//
#include <hip/hip_runtime.h>
#include <math.h>

// ---------------- constants ----------------
#define EPS 1e-5f
#define TOTAL_IN (32*512*192)   // floats per input tensor (gallery/query)
#define CPAD 176                // 171 padded to 11*16

// workspace offsets, in floats (total ~7.03M floats = 28.2 MB)
#define OFF_SIGSE 0u            // 3*192*192 = 110592
#define OFF_W1T   110592u       // 176*176   = 30976
#define OFF_QYT   141568u       // 32*176*192 = 1081344
#define OFF_KYT   1222912u      // 1081344
#define OFF_SC    2304256u      // 2048*192 = 393216
#define OFF_OUT2  2697472u      // 2048*2048 = 4194304
#define OFF_COLP  6891776u      // 32*2048*2 = 131072
#define OFF_M2V2  7022848u      // 2048*2
#define OFF_Y     7026944u      // 2048
#define OFF_SCORE 7028992u      // 1024

// ---------------- tiny kernels ----------------
__global__ void k_sigse(const float* __restrict__ se0, const float* __restrict__ se1,
                        const float* __restrict__ se2, float* __restrict__ dst) {
    int idx = blockIdx.x * 256 + threadIdx.x;
    if (idx >= 3 * 36864) return;
    int l = idx / 36864, r = idx % 36864;
    const float* se = (l == 0) ? se0 : ((l == 1) ? se1 : se2);
    float x = se[r];
    dst[idx] = 1.0f / (1.0f + __expf(-x));
}

// w1t[i][j] = (i<c && j<c) ? w1[j][i] : 0 ;  [176][176]
__global__ void k_w1t(const float* __restrict__ w1, int c, float* __restrict__ w1t) {
    int idx = blockIdx.x * 256 + threadIdx.x;
    if (idx >= CPAD * CPAD) return;
    int i = idx / CPAD, j = idx % CPAD;
    w1t[idx] = (i < c && j < c) ? w1[j * c + i] : 0.0f;
}

// ---------------- fc1: dst[b][j][t] = sum_i w1t[i][j]*inp[b][st+i][t] + b1[j] ----------------
// one block per batch b. M=176 (j), N=192 (t), K=176 (i, zero-padded rows in w1t).
__global__ __launch_bounds__(256, 2)
void k_fc1(const float* __restrict__ inp, const float* __restrict__ w1t,
           const float* __restrict__ b1, int c, int st, float* __restrict__ dst) {
    __shared__ float As[2 * 16 * CPAD];   // [16][176] per buf
    __shared__ float Bs[2 * 16 * 192];    // [16][192] per buf
    const int b = blockIdx.x;
    const int tid = threadIdx.x, ty = tid >> 4, tx = tid & 15;
    const size_t boff = (size_t)b * 98304 + (size_t)st * 192;

    float acc[11][12];
#pragma unroll
    for (int i = 0; i < 11; ++i)
#pragma unroll
        for (int j = 0; j < 12; ++j) acc[i][j] = 0.0f;

    // staging helpers (A: 704 float4, B: 768 float4, total 1472; 6 units/thread)
    float4 v[6];
    auto load_chunk = [&](int ci) {
#pragma unroll
        for (int e = 0; e < 6; ++e) {
            int f = tid + (e << 8);
            if (f < 704) {
                v[e] = *(const float4*)(w1t + ci * 2816 + f * 4);
            } else if (f < 1472) {
                size_t off = boff + (size_t)ci * 3072 + (size_t)(f - 704) * 4;
                if (off > (size_t)(TOTAL_IN - 4)) off = (size_t)(TOTAL_IN - 4); // clamp (layer2 tail)
                v[e] = *(const float4*)(inp + off);
            }
        }
    };
    auto write_chunk = [&](int buf) {
        float* Ad = As + buf * 2816;
        float* Bd = Bs + buf * 3072;
#pragma unroll
        for (int e = 0; e < 6; ++e) {
            int f = tid + (e << 8);
            if (f < 704)       *(float4*)(Ad + f * 4) = v[e];
            else if (f < 1472) *(float4*)(Bd + (f - 704) * 4) = v[e];
        }
    };

    load_chunk(0); write_chunk(0);
    __syncthreads();

    for (int ci = 0; ci < 11; ++ci) {
        const int buf = ci & 1;
        const bool pf = (ci + 1 < 11);
        if (pf) load_chunk(ci + 1);

        const float* Aw = As + buf * 2816 + ty * 11;
        const float* Bw = Bs + buf * 3072 + tx * 12;
#pragma unroll 2
        for (int kk = 0; kk < 16; ++kk) {
            const float* ar = Aw + kk * CPAD;
            float a[11];
#pragma unroll
            for (int i = 0; i < 11; ++i) a[i] = ar[i];
            const float4* bp = (const float4*)(Bw + kk * 192);
            float4 B0 = bp[0], B1 = bp[1], B2 = bp[2];
            float bb[12] = {B0.x, B0.y, B0.z, B0.w, B1.x, B1.y, B1.z, B1.w, B2.x, B2.y, B2.z, B2.w};
#pragma unroll
            for (int i = 0; i < 11; ++i)
#pragma unroll
                for (int j = 0; j < 12; ++j)
                    acc[i][j] = fmaf(a[i], bb[j], acc[i][j]);
        }
        if (pf) write_chunk(buf ^ 1);
        __syncthreads();
    }

    // epilogue: + bias (j<c), zeros for padded rows
    float* drow = dst + (size_t)b * (CPAD * 192);
#pragma unroll
    for (int i = 0; i < 11; ++i) {
        int j = ty * 11 + i;
        bool valid = (j < c);
        float bias = valid ? b1[j] : 0.0f;
        float o[12];
#pragma unroll
        for (int jj = 0; jj < 12; ++jj) o[jj] = valid ? (acc[i][jj] + bias) : 0.0f;
        float4* dp = (float4*)(drow + (size_t)j * 192 + tx * 12);
        dp[0] = make_float4(o[0], o[1], o[2], o[3]);
        dp[1] = make_float4(o[4], o[5], o[6], o[7]);
        dp[2] = make_float4(o[8], o[9], o[10], o[11]);
    }
}

// ---------------- correlation + gated max-pool ----------------
// block = (q,k) pair. vol[s][t] = sum_d kyT[k][d][s]*qyT[q][d][t] ; v = vol*sig[s][t]
// sc[2*qk][t]   = max_s v   (maxT)
// sc[2*qk+1][s] = max_t v   (maxS)
__global__ __launch_bounds__(256, 2)
void k_corr(const float* __restrict__ qyT, const float* __restrict__ kyT,
            const float* __restrict__ sig, float* __restrict__ sc) {
    __shared__ float As[2 * 3072];   // [16][192] per buf (kyT slab, s-contiguous)
    __shared__ float Bs[2 * 3072];   // [16][192] per buf (qyT slab, t-contiguous)
    const int qk = blockIdx.x;
    const int q = qk >> 5, k = qk & 31;
    const int tid = threadIdx.x, ty = tid >> 4, tx = tid & 15;
    const float* gA = kyT + (size_t)k * (CPAD * 192);
    const float* gB = qyT + (size_t)q * (CPAD * 192);

    float acc[12][12];
#pragma unroll
    for (int i = 0; i < 12; ++i)
#pragma unroll
        for (int j = 0; j < 12; ++j) acc[i][j] = 0.0f;

    float4 v[6];
    auto load_chunk = [&](int ci) {
#pragma unroll
        for (int e = 0; e < 6; ++e) {
            int f = tid + (e << 8);
            const float* src = (f < 768) ? (gA + ci * 3072 + f * 4)
                                         : (gB + ci * 3072 + (f - 768) * 4);
            v[e] = *(const float4*)src;
        }
    };
    auto write_chunk = [&](int buf) {
        float* Ad = As + buf * 3072;
        float* Bd = Bs + buf * 3072;
#pragma unroll
        for (int e = 0; e < 6; ++e) {
            int f = tid + (e << 8);
            if (f < 768) *(float4*)(Ad + f * 4) = v[e];
            else         *(float4*)(Bd + (f - 768) * 4) = v[e];
        }
    };

    load_chunk(0); write_chunk(0);
    __syncthreads();

    for (int ci = 0; ci < 11; ++ci) {
        const int buf = ci & 1;
        const bool pf = (ci + 1 < 11);
        if (pf) load_chunk(ci + 1);

        const float* Aw = As + buf * 3072 + ty * 12;
        const float* Bw = Bs + buf * 3072 + tx * 12;
#pragma unroll 2
        for (int kk = 0; kk < 16; ++kk) {
            const float4* ap = (const float4*)(Aw + kk * 192);
            const float4* bp = (const float4*)(Bw + kk * 192);
            float4 A0 = ap[0], A1 = ap[1], A2 = ap[2];
            float4 B0 = bp[0], B1 = bp[1], B2 = bp[2];
            float a[12] = {A0.x, A0.y, A0.z, A0.w, A1.x, A1.y, A1.z, A1.w, A2.x, A2.y, A2.z, A2.w};
            float b[12] = {B0.x, B0.y, B0.z, B0.w, B1.x, B1.y, B1.z, B1.w, B2.x, B2.y, B2.z, B2.w};
#pragma unroll
            for (int i = 0; i < 12; ++i)
#pragma unroll
                for (int j = 0; j < 12; ++j)
                    acc[i][j] = fmaf(a[i], b[j], acc[i][j]);
        }
        if (pf) write_chunk(buf ^ 1);
        __syncthreads();
    }

    // epilogue: gate by sigmoid(se), then dual max-reduce
    float rmax[12], cmax[12];
#pragma unroll
    for (int j = 0; j < 12; ++j) cmax[j] = -3.0e38f;
#pragma unroll
    for (int i = 0; i < 12; ++i) {
        int s = ty * 12 + i;
        const float4* sr = (const float4*)(sig + (size_t)s * 192 + tx * 12);
        float4 S0 = sr[0], S1 = sr[1], S2 = sr[2];
        float sv[12] = {S0.x, S0.y, S0.z, S0.w, S1.x, S1.y, S1.z, S1.w, S2.x, S2.y, S2.z, S2.w};
        float rm = -3.0e38f;
#pragma unroll
        for (int j = 0; j < 12; ++j) {
            float val = acc[i][j] * sv[j];
            rm = fmaxf(rm, val);
            cmax[j] = fmaxf(cmax[j], val);
        }
        rmax[i] = rm;
    }

    float* red = As;  // 16*192 floats scratch (main loop ended with barrier)
    // maxT: reduce cmax over ty groups
#pragma unroll
    for (int j = 0; j < 12; ++j) red[ty * 192 + tx * 12 + j] = cmax[j];
    __syncthreads();
    if (tid < 192) {
        float m = red[tid];
#pragma unroll
        for (int w = 1; w < 16; ++w) m = fmaxf(m, red[w * 192 + tid]);
        sc[(size_t)(2 * qk) * 192 + tid] = m;
    }
    __syncthreads();
    // maxS: reduce rmax over tx groups
#pragma unroll
    for (int i = 0; i < 12; ++i) red[tx * 192 + ty * 12 + i] = rmax[i];
    __syncthreads();
    if (tid < 192) {
        float m = red[tid];
#pragma unroll
        for (int w = 1; w < 16; ++w) m = fmaxf(m, red[w * 192 + tid]);
        sc[(size_t)(2 * qk + 1) * 192 + tid] = m;
    }
}

// ---------------- fc2: out2[r][j] = sum_t sc[r][t]*w2[j][t]  (bias/BN1 algebraically dropped) ----------------
__global__ __launch_bounds__(256, 2)
void k_fc2(const float* __restrict__ sc, const float* __restrict__ w2, float* __restrict__ out2) {
    __shared__ float Ast[32 * 132];
    __shared__ float Bst[32 * 132];
    const int bm = blockIdx.x & 15, bn = blockIdx.x >> 4;
    const int r0 = bm * 128, c0 = bn * 128;
    const int tid = threadIdx.x, ty = tid >> 4, tx = tid & 15;
    const int r = tid >> 1, half = (tid & 1) * 16;

    float acc[8][8];
#pragma unroll
    for (int i = 0; i < 8; ++i)
#pragma unroll
        for (int j = 0; j < 8; ++j) acc[i][j] = 0.0f;

    for (int t0 = 0; t0 < 192; t0 += 32) {
        float4 av[4], bv[4];
        const float4* ga = (const float4*)(sc + (size_t)(r0 + r) * 192 + t0 + half);
        const float4* gb = (const float4*)(w2 + (size_t)(c0 + r) * 192 + t0 + half);
#pragma unroll
        for (int e = 0; e < 4; ++e) { av[e] = ga[e]; bv[e] = gb[e]; }
        __syncthreads();
#pragma unroll
        for (int e = 0; e < 4; ++e) {
            int t = half + 4 * e;
            Ast[(t + 0) * 132 + r] = av[e].x;  Bst[(t + 0) * 132 + r] = bv[e].x;
            Ast[(t + 1) * 132 + r] = av[e].y;  Bst[(t + 1) * 132 + r] = bv[e].y;
            Ast[(t + 2) * 132 + r] = av[e].z;  Bst[(t + 2) * 132 + r] = bv[e].z;
            Ast[(t + 3) * 132 + r] = av[e].w;  Bst[(t + 3) * 132 + r] = bv[e].w;
        }
        __syncthreads();
#pragma unroll 4
        for (int kk = 0; kk < 32; ++kk) {
            const float4* ap = (const float4*)(Ast + kk * 132 + ty * 8);
            const float4* bp = (const float4*)(Bst + kk * 132 + tx * 8);
            float4 A0 = ap[0], A1 = ap[1];
            float4 B0 = bp[0], B1 = bp[1];
            float a[8] = {A0.x, A0.y, A0.z, A0.w, A1.x, A1.y, A1.z, A1.w};
            float b[8] = {B0.x, B0.y, B0.z, B0.w, B1.x, B1.y, B1.z, B1.w};
#pragma unroll
            for (int i = 0; i < 8; ++i)
#pragma unroll
                for (int j = 0; j < 8; ++j)
                    acc[i][j] = fmaf(a[i], b[j], acc[i][j]);
        }
    }
#pragma unroll
    for (int i = 0; i < 8; ++i) {
        float4* op = (float4*)(out2 + (size_t)(r0 + ty * 8 + i) * 2048 + c0 + tx * 8);
        op[0] = make_float4(acc[i][0], acc[i][1], acc[i][2], acc[i][3]);
        op[1] = make_float4(acc[i][4], acc[i][5], acc[i][6], acc[i][7]);
    }
}

// ---------------- BN2 column stats ----------------
__global__ void k_colp(const float* __restrict__ out2, float* __restrict__ colp) {
    const int bc = blockIdx.x & 7, br = blockIdx.x >> 3;
    const int j = bc * 256 + threadIdx.x;
    float s = 0.0f, s2 = 0.0f;
    for (int rr = br * 64; rr < br * 64 + 64; ++rr) {
        float vv = out2[(size_t)rr * 2048 + j];
        s += vv; s2 += vv * vv;
    }
    colp[((size_t)br * 2048 + j) * 2 + 0] = s;
    colp[((size_t)br * 2048 + j) * 2 + 1] = s2;
}

__global__ void k_colf(const float* __restrict__ colp, float* __restrict__ m2r2) {
    const int j = blockIdx.x * 256 + threadIdx.x;
    if (j >= 2048) return;
    float s = 0.0f, s2 = 0.0f;
    for (int br = 0; br < 32; ++br) {
        s  += colp[((size_t)br * 2048 + j) * 2 + 0];
        s2 += colp[((size_t)br * 2048 + j) * 2 + 1];
    }
    float m = s * (1.0f / 2048.0f);
    float var = s2 * (1.0f / 2048.0f) - m * m;
    m2r2[j * 2 + 0] = m;
    m2r2[j * 2 + 1] = rsqrtf(var + EPS);
}

// ---------------- fused BN2+relu+fc3 row reduction ----------------
__global__ void k_fc3(const float* __restrict__ out2, const float* __restrict__ m2r2,
                      const float* __restrict__ w3, float* __restrict__ y) {
    const int rr = blockIdx.x;
    const int tid = threadIdx.x;
    __shared__ float red[4];
    float s = 0.0f;
    for (int j = tid; j < 2048; j += 256) {
        float2 mr = ((const float2*)m2r2)[j];
        float vv = (out2[(size_t)rr * 2048 + j] - mr.x) * mr.y;
        vv = fmaxf(vv, 0.0f);
        s += vv * w3[j];
    }
#pragma unroll
    for (int off = 32; off; off >>= 1) s += __shfl_xor(s, off);
    if ((tid & 63) == 0) red[tid >> 6] = s;
    __syncthreads();
    if (tid == 0) y[rr] = red[0] + red[1] + red[2] + red[3];
}

// ---------------- pair-sum + BN3, accumulate into score ----------------
__global__ void k_bn3(const float* __restrict__ y, float* __restrict__ score, int first) {
    const int tid = threadIdx.x;
    __shared__ float rs[4], rs2[4];
    float p[4]; float s = 0.0f, s2 = 0.0f;
#pragma unroll
    for (int u = 0; u < 4; ++u) {
        int i = tid + (u << 8);
        float vv = y[2 * i] + y[2 * i + 1];
        p[u] = vv; s += vv; s2 += vv * vv;
    }
#pragma unroll
    for (int off = 32; off; off >>= 1) { s += __shfl_xor(s, off); s2 += __shfl_xor(s2, off); }
    if ((tid & 63) == 0) { rs[tid >> 6] = s; rs2[tid >> 6] = s2; }
    __syncthreads();
    float S = rs[0] + rs[1] + rs[2] + rs[3];
    float S2 = rs2[0] + rs2[1] + rs2[2] + rs2[3];
    float m = S * (1.0f / 1024.0f);
    float var = S2 * (1.0f / 1024.0f) - m * m;
    float rstd = rsqrtf(var + EPS);
#pragma unroll
    for (int u = 0; u < 4; ++u) {
        int i = tid + (u << 8);
        float vv = (p[u] - m) * rstd;
        score[i] = first ? vv : (score[i] + vv);
    }
}

// ---------------- final BN over 1024 scores ----------------
__global__ void k_final(const float* __restrict__ score, float* __restrict__ out) {
    const int tid = threadIdx.x;
    __shared__ float rs[4], rs2[4];
    float p[4]; float s = 0.0f, s2 = 0.0f;
#pragma unroll
    for (int u = 0; u < 4; ++u) {
        int i = tid + (u << 8);
        float vv = score[i];
        p[u] = vv; s += vv; s2 += vv * vv;
    }
#pragma unroll
    for (int off = 32; off; off >>= 1) { s += __shfl_xor(s, off); s2 += __shfl_xor(s2, off); }
    if ((tid & 63) == 0) { rs[tid >> 6] = s; rs2[tid >> 6] = s2; }
    __syncthreads();
    float S = rs[0] + rs[1] + rs[2] + rs[3];
    float S2 = rs2[0] + rs2[1] + rs2[2] + rs2[3];
    float m = S * (1.0f / 1024.0f);
    float var = S2 * (1.0f / 1024.0f) - m * m;
    float rstd = rsqrtf(var + EPS);
#pragma unroll
    for (int u = 0; u < 4; ++u) {
        int i = tid + (u << 8);
        out[i] = (p[u] - m) * rstd;
    }
}

// ---------------- launch ----------------
extern "C" void kernel_launch(void* const* d_in, const int* in_sizes, int n_in,
                              void* d_out, int out_size, void* d_ws, size_t ws_size,
                              hipStream_t stream) {
    const float* gallery = (const float*)d_in[0];
    const float* query   = (const float*)d_in[1];
    float* ws = (float*)d_ws;   // needs ~28.2 MB

    const int cs[3] = {171, 171, 170};
    const int st[3] = {0, 171, 342};

    k_sigse<<<(3 * 36864 + 255) / 256, 256, 0, stream>>>(
        (const float*)d_in[2 + 0 * 7 + 2], (const float*)d_in[2 + 1 * 7 + 2],
        (const float*)d_in[2 + 2 * 7 + 2], ws + OFF_SIGSE);

    for (int l = 0; l < 3; ++l) {
        const float* w1 = (const float*)d_in[2 + l * 7 + 0];
        const float* b1 = (const float*)d_in[2 + l * 7 + 1];
        const float* w2 = (const float*)d_in[2 + l * 7 + 3];
        const float* w3 = (const float*)d_in[2 + l * 7 + 5];

        k_w1t<<<(CPAD * CPAD + 255) / 256, 256, 0, stream>>>(w1, cs[l], ws + OFF_W1T);
        k_fc1<<<32, 256, 0, stream>>>(gallery, ws + OFF_W1T, b1, cs[l], st[l], ws + OFF_QYT);
        k_fc1<<<32, 256, 0, stream>>>(query,   ws + OFF_W1T, b1, cs[l], st[l], ws + OFF_KYT);
        k_corr<<<1024, 256, 0, stream>>>(ws + OFF_QYT, ws + OFF_KYT,
                                         ws + OFF_SIGSE + l * 36864, ws + OFF_SC);
        k_fc2<<<256, 256, 0, stream>>>(ws + OFF_SC, w2, ws + OFF_OUT2);
        k_colp<<<256, 256, 0, stream>>>(ws + OFF_OUT2, ws + OFF_COLP);
        k_colf<<<8, 256, 0, stream>>>(ws + OFF_COLP, ws + OFF_M2V2);
        k_fc3<<<2048, 256, 0, stream>>>(ws + OFF_OUT2, ws + OFF_M2V2, w3, ws + OFF_Y);
        k_bn3<<<1, 256, 0, stream>>>(ws + OFF_Y, ws + OFF_SCORE, l == 0 ? 1 : 0);
    }
    k_final<<<1, 256, 0, stream>>>(ws + OFF_SCORE, (float*)d_out);
}

// Round 5
// 557.260 us; speedup vs baseline: 2.0697x; 2.0697x over previous
//
#include <hip/hip_runtime.h>
#include <math.h>

// ---------------- constants ----------------
#define EPS 1e-5f
#define TOTAL_IN (32*512*192)   // floats per input tensor (gallery/query)
#define CPAD 176                // 171 padded to 11*16 (11 MFMA k-steps of 16)
#define KSTEPS 11
#define PACK_BK 6144            // shorts per (b,kstep): 2 planes * 6 tiles * 64 lanes * 8

// workspace offsets, in floats (total 7030016 floats = 28.1 MB)
#define OFF_SIGSE 0u            // 3*192*192 = 110592
#define OFF_W1T   110592u       // 176*176   = 30976
#define OFF_QPACK 141568u       // 32*11*6144 shorts = 1081344 floats
#define OFF_KPACK 1222912u      // 1081344 floats
#define OFF_SC    2304256u      // 2048*192 = 393216
#define OFF_OUT2  2697472u      // 2048*2048 = 4194304 (fc1 fp32 slabs alias its head)
#define OFF_QSLAB OFF_OUT2              // 32*176*192 = 1081344
#define OFF_KSLAB (OFF_OUT2 + 1081344u) // 1081344
#define OFF_COLP  6891776u      // 32*2048*2 = 131072
#define OFF_M2V2  7022848u      // 2048*2
#define OFF_Y     7026944u      // 2048
#define OFF_SCORE 7028992u      // 1024

typedef __attribute__((ext_vector_type(8)))  short short8;
typedef __attribute__((ext_vector_type(16))) float f32x16;

__device__ __forceinline__ unsigned short f2bf(float x) {
    unsigned u = __float_as_uint(x);
    u += 0x7fffu + ((u >> 16) & 1u);
    return (unsigned short)(u >> 16);
}
__device__ __forceinline__ float bf2f(unsigned short h) {
    return __uint_as_float(((unsigned)h) << 16);
}

__device__ __forceinline__ void g2lds16(const void* g, void* l) {
    __builtin_amdgcn_global_load_lds((const __attribute__((address_space(1))) unsigned int*)g,
                                     (__attribute__((address_space(3))) unsigned int*)l, 16, 0, 0);
}

// ---------------- tiny kernels ----------------
__global__ void k_sigse(const float* __restrict__ se0, const float* __restrict__ se1,
                        const float* __restrict__ se2, float* __restrict__ dst) {
    int idx = blockIdx.x * 256 + threadIdx.x;
    if (idx >= 3 * 36864) return;
    int l = idx / 36864, r = idx % 36864;
    const float* se = (l == 0) ? se0 : ((l == 1) ? se1 : se2);
    float x = se[r];
    dst[idx] = 1.0f / (1.0f + __expf(-x));
}

// w1t[i][j] = (i<c && j<c) ? w1[j][i] : 0 ;  [176][176]
__global__ void k_w1t(const float* __restrict__ w1, int c, float* __restrict__ w1t) {
    int idx = blockIdx.x * 256 + threadIdx.x;
    if (idx >= CPAD * CPAD) return;
    int i = idx / CPAD, j = idx % CPAD;
    w1t[idx] = (i < c && j < c) ? w1[j * c + i] : 0.0f;
}

// ---------------- fc1: slab[b][j][t] = sum_i w1t[i][j]*inp[b][st+i][t] + b1[j] ----------------
// grid (3 nquad of 64, 32 b, 2 tensor); M=176 (j), N=64 (t), K=176.
__global__ __launch_bounds__(256, 4)
void k_fc1(const float* __restrict__ g0, const float* __restrict__ g1,
           const float* __restrict__ w1t, const float* __restrict__ b1,
           int c, int st, float* __restrict__ d0, float* __restrict__ d1) {
    __shared__ float As[2 * 16 * CPAD];   // [16][176] per buf
    __shared__ float Bs[2 * 16 * 64];     // [16][64]  per buf
    const int quad = blockIdx.x, b = blockIdx.y, tensor = blockIdx.z;
    const float* inp = tensor ? g1 : g0;
    float* dst = tensor ? d1 : d0;
    const int tid = threadIdx.x, ty = tid >> 4, tx = tid & 15;
    const size_t boff = (size_t)b * 98304 + (size_t)st * 192 + (size_t)quad * 64;

    float acc[11][4];
#pragma unroll
    for (int i = 0; i < 11; ++i)
#pragma unroll
        for (int j = 0; j < 4; ++j) acc[i][j] = 0.0f;

    // staging: A 704 float4, B 256 float4 => 960 units, 4/thread
    float4 v[4];
    auto load_chunk = [&](int ci) {
#pragma unroll
        for (int e = 0; e < 4; ++e) {
            int f = tid + (e << 8);
            if (f < 704) {
                v[e] = *(const float4*)(w1t + ci * 2816 + f * 4);
            } else if (f < 960) {
                int f2 = f - 704;                 // 0..255
                int r = f2 >> 4, c4 = f2 & 15;
                size_t off = boff + (size_t)(ci * 16 + r) * 192 + c4 * 4;
                if (off > (size_t)(TOTAL_IN - 4)) off = (size_t)(TOTAL_IN - 4); // layer-2 tail clamp (A rows are 0 there)
                v[e] = *(const float4*)(inp + off);
            }
        }
    };
    auto write_chunk = [&](int buf) {
        float* Ad = As + buf * 2816;
        float* Bd = Bs + buf * 1024;
#pragma unroll
        for (int e = 0; e < 4; ++e) {
            int f = tid + (e << 8);
            if (f < 704)      *(float4*)(Ad + f * 4) = v[e];
            else if (f < 960) *(float4*)(Bd + (f - 704) * 4) = v[e];
        }
    };

    load_chunk(0); write_chunk(0);
    __syncthreads();

    for (int ci = 0; ci < 11; ++ci) {
        const int buf = ci & 1;
        const bool pf = (ci + 1 < 11);
        if (pf) load_chunk(ci + 1);

        const float* Aw = As + buf * 2816 + ty * 11;
        const float* Bw = Bs + buf * 1024 + tx * 4;
#pragma unroll 2
        for (int kk = 0; kk < 16; ++kk) {
            float a[11];
#pragma unroll
            for (int i = 0; i < 11; ++i) a[i] = Aw[kk * CPAD + i];
            float4 B0 = *(const float4*)(Bw + kk * 64);
            float bb[4] = {B0.x, B0.y, B0.z, B0.w};
#pragma unroll
            for (int i = 0; i < 11; ++i)
#pragma unroll
                for (int j = 0; j < 4; ++j)
                    acc[i][j] = fmaf(a[i], bb[j], acc[i][j]);
        }
        if (pf) write_chunk(buf ^ 1);
        __syncthreads();
    }

    float* drow = dst + (size_t)b * (CPAD * 192) + quad * 64;
#pragma unroll
    for (int i = 0; i < 11; ++i) {
        int j = ty * 11 + i;
        bool valid = (j < c);
        float bias = valid ? b1[j] : 0.0f;
        float o[4];
#pragma unroll
        for (int jj = 0; jj < 4; ++jj) o[jj] = valid ? (acc[i][jj] + bias) : 0.0f;
        *(float4*)(drow + (size_t)j * 192 + tx * 4) = make_float4(o[0], o[1], o[2], o[3]);
    }
}

// ---------------- pack: fp32 slab -> hi/lo bf16 MFMA-fragment layout ----------------
// P[b][kstep][plane][tile][lane][8]; element = slab[d = kstep*16 + 8*(lane>>5) + e][x = tile*32 + (lane&31)]
__global__ void k_pack(const float* __restrict__ qslab, const float* __restrict__ kslab,
                       short* __restrict__ qpack, short* __restrict__ kpack) {
    const int kstep = blockIdx.x, b = blockIdx.y, tensor = blockIdx.z;
    const float* src = (tensor ? kslab : qslab) + (size_t)b * (CPAD * 192);
    short* dst = (tensor ? kpack : qpack) + (size_t)(b * KSTEPS + kstep) * PACK_BK;
    const int t = threadIdx.x;              // 0..383
    const int tile = t >> 6, lane = t & 63;
    const int hf = (lane >> 5) & 1, col = lane & 31;
    const int dbase = kstep * 16 + hf * 8;
    const int x = tile * 32 + col;

    short8 H, L;
#pragma unroll
    for (int e = 0; e < 8; ++e) {
        float v = src[(size_t)(dbase + e) * 192 + x];
        unsigned short h = f2bf(v);
        unsigned short l = f2bf(v - bf2f(h));
        H[e] = (short)h;
        L[e] = (short)l;
    }
    ((short8*)dst)[(0 * 6 + tile) * 64 + lane] = H;
    ((short8*)dst)[(1 * 6 + tile) * 64 + lane] = L;
}

// ---------------- correlation + gated max-pool (split-bf16 MFMA) ----------------
// block=(q,k). vol[s][t] = sum_d ky[d][s]*qy[d][t]; gate by sig; dual max -> sc rows 2qk / 2qk+1
__global__ __launch_bounds__(256, 2)
void k_corr(const short* __restrict__ qpack, const short* __restrict__ kpack,
            const float* __restrict__ sig, float* __restrict__ sc) {
    __shared__ short smem[2 * 12288];   // per buf: A(2 planes*6 tiles*64*8) + B same = 24576 B
    const int qk = blockIdx.x, q = qk >> 5, k = qk & 31;
    const int tid = threadIdx.x, lane = tid & 63, w = tid >> 6;
    const int ws = w >> 1, wt = w & 1;
    const char* Abase = (const char*)(kpack + (size_t)k * KSTEPS * PACK_BK);
    const char* Bbase = (const char*)(qpack + (size_t)q * KSTEPS * PACK_BK);

    f32x16 acc[3][3];
#pragma unroll
    for (int i = 0; i < 3; ++i)
#pragma unroll
        for (int j = 0; j < 3; ++j)
#pragma unroll
            for (int r = 0; r < 16; ++r) acc[i][j][r] = 0.0f;

    auto stage = [&](int buf, int ks) {
#pragma unroll
        for (int u = 0; u < 6; ++u) {
            int c = u * 4 + w;   // wave-uniform chunk id, 24 x 1KB
            const char* g = (c < 12 ? Abase + (size_t)ks * 12288 + c * 1024
                                    : Bbase + (size_t)ks * 12288 + (c - 12) * 1024) + lane * 16;
            g2lds16(g, (char*)smem + buf * 24576 + c * 1024);
        }
    };

    stage(0, 0);
    __syncthreads();

    int buf = 0;
    for (int ks = 0; ks < KSTEPS; ++ks) {
        if (ks + 1 < KSTEPS) stage(buf ^ 1, ks + 1);

        const short8* LA = (const short8*)((const char*)smem + buf * 24576);
        const short8* LB = (const short8*)((const char*)smem + buf * 24576 + 12288);
        short8 Ah[3], Al[3], Bh[3], Bl[3];
#pragma unroll
        for (int u = 0; u < 3; ++u) {
            Ah[u] = LA[(0 * 6 + ws * 3 + u) * 64 + lane];
            Al[u] = LA[(1 * 6 + ws * 3 + u) * 64 + lane];
            Bh[u] = LB[(0 * 6 + wt * 3 + u) * 64 + lane];
            Bl[u] = LB[(1 * 6 + wt * 3 + u) * 64 + lane];
        }
#pragma unroll
        for (int i = 0; i < 3; ++i)
#pragma unroll
            for (int j = 0; j < 3; ++j) {
                acc[i][j] = __builtin_amdgcn_mfma_f32_32x32x16_bf16(Ah[i], Bh[j], acc[i][j], 0, 0, 0);
                acc[i][j] = __builtin_amdgcn_mfma_f32_32x32x16_bf16(Al[i], Bh[j], acc[i][j], 0, 0, 0);
                acc[i][j] = __builtin_amdgcn_mfma_f32_32x32x16_bf16(Ah[i], Bl[j], acc[i][j], 0, 0, 0);
            }
        __syncthreads();
        buf ^= 1;
    }

    // epilogue: gate + dual max.  D layout: col=lane&31, row=(r&3)+8*(r>>2)+4*(lane>>5)
    const int col = lane & 31, hf = lane >> 5;
    float* scr = (float*)smem;  // [0..384): cmax partials by ws; [384..768): rmax partials by wt
    float cm[3] = {-3.0e38f, -3.0e38f, -3.0e38f};
#pragma unroll
    for (int i = 0; i < 3; ++i) {
        const int sbase = (ws * 3 + i) * 32;
        float rv[16];
#pragma unroll
        for (int r = 0; r < 16; ++r) rv[r] = -3.0e38f;
#pragma unroll
        for (int j = 0; j < 3; ++j) {
            const int tb = (wt * 3 + j) * 32 + col;
#pragma unroll
            for (int r = 0; r < 16; ++r) {
                int row = (r & 3) + 8 * (r >> 2) + 4 * hf;
                float v = acc[i][j][r] * sig[(size_t)(sbase + row) * 192 + tb];
                rv[r] = fmaxf(rv[r], v);
                cm[j] = fmaxf(cm[j], v);
            }
        }
        // reduce rv over 32 cols (within each 32-lane half)
#pragma unroll
        for (int m = 1; m < 32; m <<= 1)
#pragma unroll
            for (int r = 0; r < 16; ++r) rv[r] = fmaxf(rv[r], __shfl_xor(rv[r], m));
        // writer: lane with col==r in each half writes row s (static indices only)
#pragma unroll
        for (int r = 0; r < 16; ++r)
            if (col == r)
                scr[384 + wt * 192 + sbase + (r & 3) + 8 * (r >> 2) + 4 * hf] = rv[r];
    }
#pragma unroll
    for (int j = 0; j < 3; ++j) {
        float c2 = fmaxf(cm[j], __shfl_xor(cm[j], 32));
        if (hf == 0) scr[ws * 192 + (wt * 3 + j) * 32 + col] = c2;
    }
    __syncthreads();
    if (tid < 192) {
        sc[(size_t)(2 * qk) * 192 + tid]     = fmaxf(scr[tid], scr[192 + tid]);
        sc[(size_t)(2 * qk + 1) * 192 + tid] = fmaxf(scr[384 + tid], scr[384 + 192 + tid]);
    }
}

// ---------------- fc2: out2[r][j] = sum_t sc[r][t]*w2[j][t]  (bias/BN1 algebraically dropped) ----------------
__global__ __launch_bounds__(256, 2)
void k_fc2(const float* __restrict__ sc, const float* __restrict__ w2, float* __restrict__ out2) {
    __shared__ float Ast[32 * 132];
    __shared__ float Bst[32 * 132];
    const int bm = blockIdx.x & 15, bn = blockIdx.x >> 4;
    const int r0 = bm * 128, c0 = bn * 128;
    const int tid = threadIdx.x, ty = tid >> 4, tx = tid & 15;
    const int r = tid >> 1, half = (tid & 1) * 16;

    float acc[8][8];
#pragma unroll
    for (int i = 0; i < 8; ++i)
#pragma unroll
        for (int j = 0; j < 8; ++j) acc[i][j] = 0.0f;

    for (int t0 = 0; t0 < 192; t0 += 32) {
        float4 av[4], bv[4];
        const float4* ga = (const float4*)(sc + (size_t)(r0 + r) * 192 + t0 + half);
        const float4* gb = (const float4*)(w2 + (size_t)(c0 + r) * 192 + t0 + half);
#pragma unroll
        for (int e = 0; e < 4; ++e) { av[e] = ga[e]; bv[e] = gb[e]; }
        __syncthreads();
#pragma unroll
        for (int e = 0; e < 4; ++e) {
            int t = half + 4 * e;
            Ast[(t + 0) * 132 + r] = av[e].x;  Bst[(t + 0) * 132 + r] = bv[e].x;
            Ast[(t + 1) * 132 + r] = av[e].y;  Bst[(t + 1) * 132 + r] = bv[e].y;
            Ast[(t + 2) * 132 + r] = av[e].z;  Bst[(t + 2) * 132 + r] = bv[e].z;
            Ast[(t + 3) * 132 + r] = av[e].w;  Bst[(t + 3) * 132 + r] = bv[e].w;
        }
        __syncthreads();
#pragma unroll 4
        for (int kk = 0; kk < 32; ++kk) {
            const float4* ap = (const float4*)(Ast + kk * 132 + ty * 8);
            const float4* bp = (const float4*)(Bst + kk * 132 + tx * 8);
            float4 A0 = ap[0], A1 = ap[1];
            float4 B0 = bp[0], B1 = bp[1];
            float a[8] = {A0.x, A0.y, A0.z, A0.w, A1.x, A1.y, A1.z, A1.w};
            float b[8] = {B0.x, B0.y, B0.z, B0.w, B1.x, B1.y, B1.z, B1.w};
#pragma unroll
            for (int i = 0; i < 8; ++i)
#pragma unroll
                for (int j = 0; j < 8; ++j)
                    acc[i][j] = fmaf(a[i], b[j], acc[i][j]);
        }
    }
#pragma unroll
    for (int i = 0; i < 8; ++i) {
        float4* op = (float4*)(out2 + (size_t)(r0 + ty * 8 + i) * 2048 + c0 + tx * 8);
        op[0] = make_float4(acc[i][0], acc[i][1], acc[i][2], acc[i][3]);
        op[1] = make_float4(acc[i][4], acc[i][5], acc[i][6], acc[i][7]);
    }
}

// ---------------- BN2 column stats ----------------
__global__ void k_colp(const float* __restrict__ out2, float* __restrict__ colp) {
    const int bc = blockIdx.x & 7, br = blockIdx.x >> 3;
    const int j = bc * 256 + threadIdx.x;
    float s = 0.0f, s2 = 0.0f;
    for (int rr = br * 64; rr < br * 64 + 64; ++rr) {
        float vv = out2[(size_t)rr * 2048 + j];
        s += vv; s2 += vv * vv;
    }
    colp[((size_t)br * 2048 + j) * 2 + 0] = s;
    colp[((size_t)br * 2048 + j) * 2 + 1] = s2;
}

__global__ void k_colf(const float* __restrict__ colp, float* __restrict__ m2r2) {
    const int j = blockIdx.x * 256 + threadIdx.x;
    if (j >= 2048) return;
    float s = 0.0f, s2 = 0.0f;
    for (int br = 0; br < 32; ++br) {
        s  += colp[((size_t)br * 2048 + j) * 2 + 0];
        s2 += colp[((size_t)br * 2048 + j) * 2 + 1];
    }
    float m = s * (1.0f / 2048.0f);
    float var = s2 * (1.0f / 2048.0f) - m * m;
    m2r2[j * 2 + 0] = m;
    m2r2[j * 2 + 1] = rsqrtf(var + EPS);
}

// ---------------- fused BN2+relu+fc3 row reduction ----------------
__global__ void k_fc3(const float* __restrict__ out2, const float* __restrict__ m2r2,
                      const float* __restrict__ w3, float* __restrict__ y) {
    const int rr = blockIdx.x;
    const int tid = threadIdx.x;
    __shared__ float red[4];
    float s = 0.0f;
    for (int j = tid; j < 2048; j += 256) {
        float2 mr = ((const float2*)m2r2)[j];
        float vv = (out2[(size_t)rr * 2048 + j] - mr.x) * mr.y;
        vv = fmaxf(vv, 0.0f);
        s += vv * w3[j];
    }
#pragma unroll
    for (int off = 32; off; off >>= 1) s += __shfl_xor(s, off);
    if ((tid & 63) == 0) red[tid >> 6] = s;
    __syncthreads();
    if (tid == 0) y[rr] = red[0] + red[1] + red[2] + red[3];
}

// ---------------- pair-sum + BN3, accumulate into score ----------------
__global__ void k_bn3(const float* __restrict__ y, float* __restrict__ score, int first) {
    const int tid = threadIdx.x;
    __shared__ float rs[4], rs2[4];
    float p[4]; float s = 0.0f, s2 = 0.0f;
#pragma unroll
    for (int u = 0; u < 4; ++u) {
        int i = tid + (u << 8);
        float vv = y[2 * i] + y[2 * i + 1];
        p[u] = vv; s += vv; s2 += vv * vv;
    }
#pragma unroll
    for (int off = 32; off; off >>= 1) { s += __shfl_xor(s, off); s2 += __shfl_xor(s2, off); }
    if ((tid & 63) == 0) { rs[tid >> 6] = s; rs2[tid >> 6] = s2; }
    __syncthreads();
    float S = rs[0] + rs[1] + rs[2] + rs[3];
    float S2 = rs2[0] + rs2[1] + rs2[2] + rs2[3];
    float m = S * (1.0f / 1024.0f);
    float var = S2 * (1.0f / 1024.0f) - m * m;
    float rstd = rsqrtf(var + EPS);
#pragma unroll
    for (int u = 0; u < 4; ++u) {
        int i = tid + (u << 8);
        float vv = (p[u] - m) * rstd;
        score[i] = first ? vv : (score[i] + vv);
    }
}

// ---------------- final BN over 1024 scores ----------------
__global__ void k_final(const float* __restrict__ score, float* __restrict__ out) {
    const int tid = threadIdx.x;
    __shared__ float rs[4], rs2[4];
    float p[4]; float s = 0.0f, s2 = 0.0f;
#pragma unroll
    for (int u = 0; u < 4; ++u) {
        int i = tid + (u << 8);
        float vv = score[i];
        p[u] = vv; s += vv; s2 += vv * vv;
    }
#pragma unroll
    for (int off = 32; off; off >>= 1) { s += __shfl_xor(s, off); s2 += __shfl_xor(s2, off); }
    if ((tid & 63) == 0) { rs[tid >> 6] = s; rs2[tid >> 6] = s2; }
    __syncthreads();
    float S = rs[0] + rs[1] + rs[2] + rs[3];
    float S2 = rs2[0] + rs2[1] + rs2[2] + rs2[3];
    float m = S * (1.0f / 1024.0f);
    float var = S2 * (1.0f / 1024.0f) - m * m;
    float rstd = rsqrtf(var + EPS);
#pragma unroll
    for (int u = 0; u < 4; ++u) {
        int i = tid + (u << 8);
        out[i] = (p[u] - m) * rstd;
    }
}

// ---------------- launch ----------------
extern "C" void kernel_launch(void* const* d_in, const int* in_sizes, int n_in,
                              void* d_out, int out_size, void* d_ws, size_t ws_size,
                              hipStream_t stream) {
    const float* gallery = (const float*)d_in[0];
    const float* query   = (const float*)d_in[1];
    float* ws = (float*)d_ws;   // needs ~28.2 MB

    const int cs[3] = {171, 171, 170};
    const int st[3] = {0, 171, 342};

    short* qpack = (short*)(ws + OFF_QPACK);
    short* kpack = (short*)(ws + OFF_KPACK);

    k_sigse<<<(3 * 36864 + 255) / 256, 256, 0, stream>>>(
        (const float*)d_in[2 + 0 * 7 + 2], (const float*)d_in[2 + 1 * 7 + 2],
        (const float*)d_in[2 + 2 * 7 + 2], ws + OFF_SIGSE);

    for (int l = 0; l < 3; ++l) {
        const float* w1 = (const float*)d_in[2 + l * 7 + 0];
        const float* b1 = (const float*)d_in[2 + l * 7 + 1];
        const float* w2 = (const float*)d_in[2 + l * 7 + 3];
        const float* w3 = (const float*)d_in[2 + l * 7 + 5];

        k_w1t<<<(CPAD * CPAD + 255) / 256, 256, 0, stream>>>(w1, cs[l], ws + OFF_W1T);
        k_fc1<<<dim3(3, 32, 2), 256, 0, stream>>>(gallery, query, ws + OFF_W1T, b1,
                                                  cs[l], st[l], ws + OFF_QSLAB, ws + OFF_KSLAB);
        k_pack<<<dim3(KSTEPS, 32, 2), 384, 0, stream>>>(ws + OFF_QSLAB, ws + OFF_KSLAB,
                                                        qpack, kpack);
        k_corr<<<1024, 256, 0, stream>>>(qpack, kpack, ws + OFF_SIGSE + l * 36864, ws + OFF_SC);
        k_fc2<<<256, 256, 0, stream>>>(ws + OFF_SC, w2, ws + OFF_OUT2);
        k_colp<<<256, 256, 0, stream>>>(ws + OFF_OUT2, ws + OFF_COLP);
        k_colf<<<8, 256, 0, stream>>>(ws + OFF_COLP, ws + OFF_M2V2);
        k_fc3<<<2048, 256, 0, stream>>>(ws + OFF_OUT2, ws + OFF_M2V2, w3, ws + OFF_Y);
        k_bn3<<<1, 256, 0, stream>>>(ws + OFF_Y, ws + OFF_SCORE, l == 0 ? 1 : 0);
    }
    k_final<<<1, 256, 0, stream>>>(ws + OFF_SCORE, (float*)d_out);
}

// Round 6
// 389.044 us; speedup vs baseline: 2.9646x; 1.4324x over previous
//
#include <hip/hip_runtime.h>
#include <math.h>

// ---------------- constants ----------------
#define EPS 1e-5f
#define TOTAL_IN (32*512*192)   // floats per input tensor (gallery/query)
#define CPAD 176                // 171 padded to 11*16 (11 MFMA k-steps of 16)
#define KSTEPS 11
#define PACK_BK 6144            // shorts per (b,kstep): 2 planes * 6 tiles * 64 lanes * 8

// ======== fallback (per-layer) workspace offsets, floats (28.1 MB) ========
#define OFF_SIGSE 0u            // 3*192*192 = 110592
#define OFF_W1T   110592u       // 176*176   = 30976
#define OFF_QPACK 141568u       // 32*11*6144 shorts = 1081344 floats
#define OFF_KPACK 1222912u      // 1081344 floats
#define OFF_SC    2304256u      // 2048*192 = 393216
#define OFF_OUT2  2697472u      // 2048*2048 = 4194304 (fc1 fp32 slabs alias its head)
#define OFF_QSLAB OFF_OUT2              // 32*176*192 = 1081344
#define OFF_KSLAB (OFF_OUT2 + 1081344u) // 1081344
#define OFF_COLP  6891776u      // 32*2048*2 = 131072
#define OFF_M2V2  7022848u      // 2048*2
#define OFF_Y     7026944u      // 2048
#define OFF_SCORE 7028992u      // 1024

// ======== batched (3-layer) workspace offsets, floats (58.3 MB) ========
#define B_SIGSE 0u              // 3*36864 = 110592
#define B_W1T   110592u         // 3*30976 = 92928
#define B_SC    203520u         // 3*393216 = 1179648
#define B_COLP  1383168u        // 3*16*2048*2 = 196608
#define B_M2R2  1579776u        // 3*4096 = 12288
#define B_Y     1592064u        // 3*2048 = 6144
#define B_SC3   1598208u        // 3*1024 = 3072
#define B_BIG   1601280u        // region: slabs(6488064)+packs(6488064), reused by out2(12582912)
#define B_SLAB  B_BIG                   // [l][tensor] stride 1081344 floats
#define B_PACKF (B_BIG + 6488064u)      // packs as float offset; [l][tensor] stride 2162688 shorts
#define B_OUT2  B_BIG                   // [l] stride 4194304 floats
#define B_TOTAL 14577408u       // floats -> 58,309,632 bytes

typedef __attribute__((ext_vector_type(8)))  short short8;
typedef __attribute__((ext_vector_type(16))) float f32x16;

__device__ __forceinline__ unsigned short f2bf(float x) {
    unsigned u = __float_as_uint(x);
    u += 0x7fffu + ((u >> 16) & 1u);
    return (unsigned short)(u >> 16);
}
__device__ __forceinline__ float bf2f(unsigned short h) {
    return __uint_as_float(((unsigned)h) << 16);
}

__device__ __forceinline__ void g2lds16(const void* g, void* l) {
    __builtin_amdgcn_global_load_lds((const __attribute__((address_space(1))) unsigned int*)g,
                                     (__attribute__((address_space(3))) unsigned int*)l, 16, 0, 0);
}

// ---------------- shared tiny kernel ----------------
__global__ void k_sigse(const float* __restrict__ se0, const float* __restrict__ se1,
                        const float* __restrict__ se2, float* __restrict__ dst) {
    int idx = blockIdx.x * 256 + threadIdx.x;
    if (idx >= 3 * 36864) return;
    int l = idx / 36864, r = idx % 36864;
    const float* se = (l == 0) ? se0 : ((l == 1) ? se1 : se2);
    float x = se[r];
    dst[idx] = 1.0f / (1.0f + __expf(-x));
}

// ================================================================
//                      BATCHED (3-layer) PATH
// ================================================================

// w1t[l][i][j] = (i<c && j<c) ? w1_l[j][i] : 0
__global__ void k_w1t_b(const float* __restrict__ w1_0, const float* __restrict__ w1_1,
                        const float* __restrict__ w1_2, float* __restrict__ w1t) {
    int idx = blockIdx.x * 256 + threadIdx.x;
    if (idx >= 3 * CPAD * CPAD) return;
    int l = idx / (CPAD * CPAD), r = idx % (CPAD * CPAD);
    int i = r / CPAD, j = r % CPAD;
    int c = (l == 2) ? 170 : 171;
    const float* w1 = (l == 0) ? w1_0 : ((l == 1) ? w1_1 : w1_2);
    w1t[idx] = (i < c && j < c) ? w1[j * c + i] : 0.0f;
}

// fc1 batched: grid (3 quad, 32 b, 6=l*2+tensor)
__global__ __launch_bounds__(256, 4)
void k_fc1_b(const float* __restrict__ g0, const float* __restrict__ g1,
             const float* __restrict__ w1tb,
             const float* __restrict__ b1_0, const float* __restrict__ b1_1,
             const float* __restrict__ b1_2, float* __restrict__ slabs) {
    __shared__ float As[2 * 16 * CPAD];
    __shared__ float Bs[2 * 16 * 64];
    const int quad = blockIdx.x, b = blockIdx.y, z = blockIdx.z;
    const int l = z >> 1, tensor = z & 1;
    const int c = (l == 2) ? 170 : 171, st = l * 171;
    const float* inp = tensor ? g1 : g0;
    const float* w1t = w1tb + (unsigned)l * (CPAD * CPAD);
    const float* b1 = (l == 0) ? b1_0 : ((l == 1) ? b1_1 : b1_2);
    float* dst = slabs + (size_t)z * 1081344u;
    const int tid = threadIdx.x, ty = tid >> 4, tx = tid & 15;
    const size_t boff = (size_t)b * 98304 + (size_t)st * 192 + (size_t)quad * 64;

    float acc[11][4];
#pragma unroll
    for (int i = 0; i < 11; ++i)
#pragma unroll
        for (int j = 0; j < 4; ++j) acc[i][j] = 0.0f;

    float4 v[4];
    auto load_chunk = [&](int ci) {
#pragma unroll
        for (int e = 0; e < 4; ++e) {
            int f = tid + (e << 8);
            if (f < 704) {
                v[e] = *(const float4*)(w1t + ci * 2816 + f * 4);
            } else if (f < 960) {
                int f2 = f - 704;
                int r = f2 >> 4, c4 = f2 & 15;
                size_t off = boff + (size_t)(ci * 16 + r) * 192 + c4 * 4;
                if (off > (size_t)(TOTAL_IN - 4)) off = (size_t)(TOTAL_IN - 4); // layer-2 tail clamp (A rows are 0 there)
                v[e] = *(const float4*)(inp + off);
            }
        }
    };
    auto write_chunk = [&](int buf) {
        float* Ad = As + buf * 2816;
        float* Bd = Bs + buf * 1024;
#pragma unroll
        for (int e = 0; e < 4; ++e) {
            int f = tid + (e << 8);
            if (f < 704)      *(float4*)(Ad + f * 4) = v[e];
            else if (f < 960) *(float4*)(Bd + (f - 704) * 4) = v[e];
        }
    };

    load_chunk(0); write_chunk(0);
    __syncthreads();

    for (int ci = 0; ci < 11; ++ci) {
        const int buf = ci & 1;
        const bool pf = (ci + 1 < 11);
        if (pf) load_chunk(ci + 1);

        const float* Aw = As + buf * 2816 + ty * 11;
        const float* Bw = Bs + buf * 1024 + tx * 4;
#pragma unroll 2
        for (int kk = 0; kk < 16; ++kk) {
            float a[11];
#pragma unroll
            for (int i = 0; i < 11; ++i) a[i] = Aw[kk * CPAD + i];
            float4 B0 = *(const float4*)(Bw + kk * 64);
            float bb[4] = {B0.x, B0.y, B0.z, B0.w};
#pragma unroll
            for (int i = 0; i < 11; ++i)
#pragma unroll
                for (int j = 0; j < 4; ++j)
                    acc[i][j] = fmaf(a[i], bb[j], acc[i][j]);
        }
        if (pf) write_chunk(buf ^ 1);
        __syncthreads();
    }

    float* drow = dst + (size_t)b * (CPAD * 192) + quad * 64;
#pragma unroll
    for (int i = 0; i < 11; ++i) {
        int j = ty * 11 + i;
        bool valid = (j < c);
        float bias = valid ? b1[j] : 0.0f;
        float o[4];
#pragma unroll
        for (int jj = 0; jj < 4; ++jj) o[jj] = valid ? (acc[i][jj] + bias) : 0.0f;
        *(float4*)(drow + (size_t)j * 192 + tx * 4) = make_float4(o[0], o[1], o[2], o[3]);
    }
}

// pack batched: grid (11, 32, 6=l*2+tensor)
__global__ void k_pack_b(const float* __restrict__ slabs, short* __restrict__ packs) {
    const int kstep = blockIdx.x, b = blockIdx.y, z = blockIdx.z;
    const float* src = slabs + (size_t)z * 1081344u + (size_t)b * (CPAD * 192);
    short* dst = packs + (size_t)z * 2162688u + (size_t)(b * KSTEPS + kstep) * PACK_BK;
    const int t = threadIdx.x;              // 0..383
    const int tile = t >> 6, lane = t & 63;
    const int hf = (lane >> 5) & 1, col = lane & 31;
    const int dbase = kstep * 16 + hf * 8;
    const int x = tile * 32 + col;

    short8 H, L;
#pragma unroll
    for (int e = 0; e < 8; ++e) {
        float v = src[(size_t)(dbase + e) * 192 + x];
        unsigned short h = f2bf(v);
        unsigned short l = f2bf(v - bf2f(h));
        H[e] = (short)h;
        L[e] = (short)l;
    }
    ((short8*)dst)[(0 * 6 + tile) * 64 + lane] = H;
    ((short8*)dst)[(1 * 6 + tile) * 64 + lane] = L;
}

// corr batched: grid (1024, 3)
__global__ __launch_bounds__(256, 2)
void k_corr_b(const short* __restrict__ packs, const float* __restrict__ sigb,
              float* __restrict__ scb) {
    __shared__ short smem[2 * 12288];
    const int qk = blockIdx.x, l = blockIdx.y;
    const int q = qk >> 5, k = qk & 31;
    const int tid = threadIdx.x, lane = tid & 63, w = tid >> 6;
    const int ws = w >> 1, wt = w & 1;
    const short* qpack = packs + (size_t)(l * 2 + 0) * 2162688u;
    const short* kpack = packs + (size_t)(l * 2 + 1) * 2162688u;
    const float* sig = sigb + (unsigned)l * 36864u;
    float* sc = scb + (size_t)l * 393216u;
    const char* Abase = (const char*)(kpack + (size_t)k * KSTEPS * PACK_BK);
    const char* Bbase = (const char*)(qpack + (size_t)q * KSTEPS * PACK_BK);

    f32x16 acc[3][3];
#pragma unroll
    for (int i = 0; i < 3; ++i)
#pragma unroll
        for (int j = 0; j < 3; ++j)
#pragma unroll
            for (int r = 0; r < 16; ++r) acc[i][j][r] = 0.0f;

    auto stage = [&](int buf, int ks) {
#pragma unroll
        for (int u = 0; u < 6; ++u) {
            int c = u * 4 + w;
            const char* g = (c < 12 ? Abase + (size_t)ks * 12288 + c * 1024
                                    : Bbase + (size_t)ks * 12288 + (c - 12) * 1024) + lane * 16;
            g2lds16(g, (char*)smem + buf * 24576 + c * 1024);
        }
    };

    stage(0, 0);
    __syncthreads();

    int buf = 0;
    for (int ks = 0; ks < KSTEPS; ++ks) {
        if (ks + 1 < KSTEPS) stage(buf ^ 1, ks + 1);

        const short8* LA = (const short8*)((const char*)smem + buf * 24576);
        const short8* LB = (const short8*)((const char*)smem + buf * 24576 + 12288);
        short8 Ah[3], Al[3], Bh[3], Bl[3];
#pragma unroll
        for (int u = 0; u < 3; ++u) {
            Ah[u] = LA[(0 * 6 + ws * 3 + u) * 64 + lane];
            Al[u] = LA[(1 * 6 + ws * 3 + u) * 64 + lane];
            Bh[u] = LB[(0 * 6 + wt * 3 + u) * 64 + lane];
            Bl[u] = LB[(1 * 6 + wt * 3 + u) * 64 + lane];
        }
#pragma unroll
        for (int i = 0; i < 3; ++i)
#pragma unroll
            for (int j = 0; j < 3; ++j) {
                acc[i][j] = __builtin_amdgcn_mfma_f32_32x32x16_bf16(Ah[i], Bh[j], acc[i][j], 0, 0, 0);
                acc[i][j] = __builtin_amdgcn_mfma_f32_32x32x16_bf16(Al[i], Bh[j], acc[i][j], 0, 0, 0);
                acc[i][j] = __builtin_amdgcn_mfma_f32_32x32x16_bf16(Ah[i], Bl[j], acc[i][j], 0, 0, 0);
            }
        __syncthreads();
        buf ^= 1;
    }

    const int col = lane & 31, hf = lane >> 5;
    float* scr = (float*)smem;
    float cm[3] = {-3.0e38f, -3.0e38f, -3.0e38f};
#pragma unroll
    for (int i = 0; i < 3; ++i) {
        const int sbase = (ws * 3 + i) * 32;
        float rv[16];
#pragma unroll
        for (int r = 0; r < 16; ++r) rv[r] = -3.0e38f;
#pragma unroll
        for (int j = 0; j < 3; ++j) {
            const int tb = (wt * 3 + j) * 32 + col;
#pragma unroll
            for (int r = 0; r < 16; ++r) {
                int row = (r & 3) + 8 * (r >> 2) + 4 * hf;
                float v = acc[i][j][r] * sig[(size_t)(sbase + row) * 192 + tb];
                rv[r] = fmaxf(rv[r], v);
                cm[j] = fmaxf(cm[j], v);
            }
        }
#pragma unroll
        for (int m = 1; m < 32; m <<= 1)
#pragma unroll
            for (int r = 0; r < 16; ++r) rv[r] = fmaxf(rv[r], __shfl_xor(rv[r], m));
#pragma unroll
        for (int r = 0; r < 16; ++r)
            if (col == r)
                scr[384 + wt * 192 + sbase + (r & 3) + 8 * (r >> 2) + 4 * hf] = rv[r];
    }
#pragma unroll
    for (int j = 0; j < 3; ++j) {
        float c2 = fmaxf(cm[j], __shfl_xor(cm[j], 32));
        if (hf == 0) scr[ws * 192 + (wt * 3 + j) * 32 + col] = c2;
    }
    __syncthreads();
    if (tid < 192) {
        sc[(size_t)(2 * qk) * 192 + tid]     = fmaxf(scr[tid], scr[192 + tid]);
        sc[(size_t)(2 * qk + 1) * 192 + tid] = fmaxf(scr[384 + tid], scr[384 + 192 + tid]);
    }
}

// fc2 batched + fused BN2 column partials: grid (256, 3)
__global__ __launch_bounds__(256, 2)
void k_fc2c_b(const float* __restrict__ scb,
              const float* __restrict__ w2_0, const float* __restrict__ w2_1,
              const float* __restrict__ w2_2,
              float* __restrict__ out2b, float* __restrict__ colpb) {
    __shared__ float Ast[32 * 132];
    __shared__ float Bst[32 * 132];
    const int bm = blockIdx.x & 15, bn = blockIdx.x >> 4, l = blockIdx.y;
    const float* sc = scb + (size_t)l * 393216u;
    const float* w2 = (l == 0) ? w2_0 : ((l == 1) ? w2_1 : w2_2);
    float* out2 = out2b + (size_t)l * 4194304u;
    float* colp = colpb + (size_t)l * 65536u;
    const int r0 = bm * 128, c0 = bn * 128;
    const int tid = threadIdx.x, ty = tid >> 4, tx = tid & 15;
    const int r = tid >> 1, half = (tid & 1) * 16;

    float acc[8][8];
#pragma unroll
    for (int i = 0; i < 8; ++i)
#pragma unroll
        for (int j = 0; j < 8; ++j) acc[i][j] = 0.0f;

    for (int t0 = 0; t0 < 192; t0 += 32) {
        float4 av[4], bv[4];
        const float4* ga = (const float4*)(sc + (size_t)(r0 + r) * 192 + t0 + half);
        const float4* gb = (const float4*)(w2 + (size_t)(c0 + r) * 192 + t0 + half);
#pragma unroll
        for (int e = 0; e < 4; ++e) { av[e] = ga[e]; bv[e] = gb[e]; }
        __syncthreads();
#pragma unroll
        for (int e = 0; e < 4; ++e) {
            int t = half + 4 * e;
            Ast[(t + 0) * 132 + r] = av[e].x;  Bst[(t + 0) * 132 + r] = bv[e].x;
            Ast[(t + 1) * 132 + r] = av[e].y;  Bst[(t + 1) * 132 + r] = bv[e].y;
            Ast[(t + 2) * 132 + r] = av[e].z;  Bst[(t + 2) * 132 + r] = bv[e].z;
            Ast[(t + 3) * 132 + r] = av[e].w;  Bst[(t + 3) * 132 + r] = bv[e].w;
        }
        __syncthreads();
#pragma unroll 4
        for (int kk = 0; kk < 32; ++kk) {
            const float4* ap = (const float4*)(Ast + kk * 132 + ty * 8);
            const float4* bp = (const float4*)(Bst + kk * 132 + tx * 8);
            float4 A0 = ap[0], A1 = ap[1];
            float4 B0 = bp[0], B1 = bp[1];
            float a[8] = {A0.x, A0.y, A0.z, A0.w, A1.x, A1.y, A1.z, A1.w};
            float b[8] = {B0.x, B0.y, B0.z, B0.w, B1.x, B1.y, B1.z, B1.w};
#pragma unroll
            for (int i = 0; i < 8; ++i)
#pragma unroll
                for (int j = 0; j < 8; ++j)
                    acc[i][j] = fmaf(a[i], b[j], acc[i][j]);
        }
    }
#pragma unroll
    for (int i = 0; i < 8; ++i) {
        float4* op = (float4*)(out2 + (size_t)(r0 + ty * 8 + i) * 2048 + c0 + tx * 8);
        op[0] = make_float4(acc[i][0], acc[i][1], acc[i][2], acc[i][3]);
        op[1] = make_float4(acc[i][4], acc[i][5], acc[i][6], acc[i][7]);
    }
    // fused BN2 column partials for this 128-row x 128-col tile
    float cs_[8], cq_[8];
#pragma unroll
    for (int jj = 0; jj < 8; ++jj) {
        float s = 0.0f, q2 = 0.0f;
#pragma unroll
        for (int i = 0; i < 8; ++i) { float v = acc[i][jj]; s += v; q2 += v * v; }
        cs_[jj] = s; cq_[jj] = q2;
    }
    __syncthreads();   // main-loop LDS reads complete before scratch reuse
#pragma unroll
    for (int jj = 0; jj < 8; ++jj) {
        Ast[ty * 128 + tx * 8 + jj] = cs_[jj];
        Bst[ty * 128 + tx * 8 + jj] = cq_[jj];
    }
    __syncthreads();
    if (tid < 128) {
        float s = 0.0f, q2 = 0.0f;
#pragma unroll
        for (int wv = 0; wv < 16; ++wv) { s += Ast[wv * 128 + tid]; q2 += Bst[wv * 128 + tid]; }
        colp[((size_t)bm * 2048 + c0 + tid) * 2 + 0] = s;
        colp[((size_t)bm * 2048 + c0 + tid) * 2 + 1] = q2;
    }
}

// reduce 16 row-block partials -> mean/rstd per (l, j). grid 24
__global__ void k_colf_b(const float* __restrict__ colpb, float* __restrict__ m2r2b) {
    const int idx = blockIdx.x * 256 + threadIdx.x;
    if (idx >= 3 * 2048) return;
    const int l = idx >> 11, j = idx & 2047;
    const float* colp = colpb + (size_t)l * 65536u;
    float s = 0.0f, s2 = 0.0f;
    for (int bm = 0; bm < 16; ++bm) {
        s  += colp[((size_t)bm * 2048 + j) * 2 + 0];
        s2 += colp[((size_t)bm * 2048 + j) * 2 + 1];
    }
    float m = s * (1.0f / 2048.0f);
    float var = s2 * (1.0f / 2048.0f) - m * m;
    m2r2b[(size_t)l * 4096 + j * 2 + 0] = m;
    m2r2b[(size_t)l * 4096 + j * 2 + 1] = rsqrtf(var + EPS);
}

// fused BN2+relu+fc3: grid (2048, 3)
__global__ void k_fc3_b(const float* __restrict__ out2b, const float* __restrict__ m2r2b,
                        const float* __restrict__ w3_0, const float* __restrict__ w3_1,
                        const float* __restrict__ w3_2, float* __restrict__ yb) {
    const int rr = blockIdx.x, l = blockIdx.y;
    const float* out2 = out2b + (size_t)l * 4194304u;
    const float* m2r2 = m2r2b + (size_t)l * 4096u;
    const float* w3 = (l == 0) ? w3_0 : ((l == 1) ? w3_1 : w3_2);
    const int tid = threadIdx.x;
    __shared__ float red[4];
    float s = 0.0f;
    for (int j = tid; j < 2048; j += 256) {
        float2 mr = ((const float2*)m2r2)[j];
        float vv = (out2[(size_t)rr * 2048 + j] - mr.x) * mr.y;
        vv = fmaxf(vv, 0.0f);
        s += vv * w3[j];
    }
#pragma unroll
    for (int off = 32; off; off >>= 1) s += __shfl_xor(s, off);
    if ((tid & 63) == 0) red[tid >> 6] = s;
    __syncthreads();
    if (tid == 0) yb[(size_t)l * 2048 + rr] = red[0] + red[1] + red[2] + red[3];
}

// pair-sum + BN3 per layer: grid 3
__global__ void k_bn3_b(const float* __restrict__ yb, float* __restrict__ sc3) {
    const int l = blockIdx.x, tid = threadIdx.x;
    const float* y = yb + (size_t)l * 2048u;
    __shared__ float rs[4], rs2[4];
    float p[4]; float s = 0.0f, s2 = 0.0f;
#pragma unroll
    for (int u = 0; u < 4; ++u) {
        int i = tid + (u << 8);
        float vv = y[2 * i] + y[2 * i + 1];
        p[u] = vv; s += vv; s2 += vv * vv;
    }
#pragma unroll
    for (int off = 32; off; off >>= 1) { s += __shfl_xor(s, off); s2 += __shfl_xor(s2, off); }
    if ((tid & 63) == 0) { rs[tid >> 6] = s; rs2[tid >> 6] = s2; }
    __syncthreads();
    float S = rs[0] + rs[1] + rs[2] + rs[3];
    float S2 = rs2[0] + rs2[1] + rs2[2] + rs2[3];
    float m = S * (1.0f / 1024.0f);
    float var = S2 * (1.0f / 1024.0f) - m * m;
    float rstd = rsqrtf(var + EPS);
#pragma unroll
    for (int u = 0; u < 4; ++u) {
        int i = tid + (u << 8);
        sc3[(size_t)l * 1024 + i] = (p[u] - m) * rstd;
    }
}

// sum 3 layers + final BN
__global__ void k_final3(const float* __restrict__ sc3, float* __restrict__ out) {
    const int tid = threadIdx.x;
    __shared__ float rs[4], rs2[4];
    float p[4]; float s = 0.0f, s2 = 0.0f;
#pragma unroll
    for (int u = 0; u < 4; ++u) {
        int i = tid + (u << 8);
        float vv = sc3[i] + sc3[1024 + i] + sc3[2048 + i];
        p[u] = vv; s += vv; s2 += vv * vv;
    }
#pragma unroll
    for (int off = 32; off; off >>= 1) { s += __shfl_xor(s, off); s2 += __shfl_xor(s2, off); }
    if ((tid & 63) == 0) { rs[tid >> 6] = s; rs2[tid >> 6] = s2; }
    __syncthreads();
    float S = rs[0] + rs[1] + rs[2] + rs[3];
    float S2 = rs2[0] + rs2[1] + rs2[2] + rs2[3];
    float m = S * (1.0f / 1024.0f);
    float var = S2 * (1.0f / 1024.0f) - m * m;
    float rstd = rsqrtf(var + EPS);
#pragma unroll
    for (int u = 0; u < 4; ++u) {
        int i = tid + (u << 8);
        out[i] = (p[u] - m) * rstd;
    }
}

// ================================================================
//              FALLBACK (per-layer) PATH — proven R5 code
// ================================================================

__global__ void k_w1t(const float* __restrict__ w1, int c, float* __restrict__ w1t) {
    int idx = blockIdx.x * 256 + threadIdx.x;
    if (idx >= CPAD * CPAD) return;
    int i = idx / CPAD, j = idx % CPAD;
    w1t[idx] = (i < c && j < c) ? w1[j * c + i] : 0.0f;
}

__global__ __launch_bounds__(256, 4)
void k_fc1(const float* __restrict__ g0, const float* __restrict__ g1,
           const float* __restrict__ w1t, const float* __restrict__ b1,
           int c, int st, float* __restrict__ d0, float* __restrict__ d1) {
    __shared__ float As[2 * 16 * CPAD];
    __shared__ float Bs[2 * 16 * 64];
    const int quad = blockIdx.x, b = blockIdx.y, tensor = blockIdx.z;
    const float* inp = tensor ? g1 : g0;
    float* dst = tensor ? d1 : d0;
    const int tid = threadIdx.x, ty = tid >> 4, tx = tid & 15;
    const size_t boff = (size_t)b * 98304 + (size_t)st * 192 + (size_t)quad * 64;

    float acc[11][4];
#pragma unroll
    for (int i = 0; i < 11; ++i)
#pragma unroll
        for (int j = 0; j < 4; ++j) acc[i][j] = 0.0f;

    float4 v[4];
    auto load_chunk = [&](int ci) {
#pragma unroll
        for (int e = 0; e < 4; ++e) {
            int f = tid + (e << 8);
            if (f < 704) {
                v[e] = *(const float4*)(w1t + ci * 2816 + f * 4);
            } else if (f < 960) {
                int f2 = f - 704;
                int r = f2 >> 4, c4 = f2 & 15;
                size_t off = boff + (size_t)(ci * 16 + r) * 192 + c4 * 4;
                if (off > (size_t)(TOTAL_IN - 4)) off = (size_t)(TOTAL_IN - 4);
                v[e] = *(const float4*)(inp + off);
            }
        }
    };
    auto write_chunk = [&](int buf) {
        float* Ad = As + buf * 2816;
        float* Bd = Bs + buf * 1024;
#pragma unroll
        for (int e = 0; e < 4; ++e) {
            int f = tid + (e << 8);
            if (f < 704)      *(float4*)(Ad + f * 4) = v[e];
            else if (f < 960) *(float4*)(Bd + (f - 704) * 4) = v[e];
        }
    };

    load_chunk(0); write_chunk(0);
    __syncthreads();

    for (int ci = 0; ci < 11; ++ci) {
        const int buf = ci & 1;
        const bool pf = (ci + 1 < 11);
        if (pf) load_chunk(ci + 1);

        const float* Aw = As + buf * 2816 + ty * 11;
        const float* Bw = Bs + buf * 1024 + tx * 4;
#pragma unroll 2
        for (int kk = 0; kk < 16; ++kk) {
            float a[11];
#pragma unroll
            for (int i = 0; i < 11; ++i) a[i] = Aw[kk * CPAD + i];
            float4 B0 = *(const float4*)(Bw + kk * 64);
            float bb[4] = {B0.x, B0.y, B0.z, B0.w};
#pragma unroll
            for (int i = 0; i < 11; ++i)
#pragma unroll
                for (int j = 0; j < 4; ++j)
                    acc[i][j] = fmaf(a[i], bb[j], acc[i][j]);
        }
        if (pf) write_chunk(buf ^ 1);
        __syncthreads();
    }

    float* drow = dst + (size_t)b * (CPAD * 192) + quad * 64;
#pragma unroll
    for (int i = 0; i < 11; ++i) {
        int j = ty * 11 + i;
        bool valid = (j < c);
        float bias = valid ? b1[j] : 0.0f;
        float o[4];
#pragma unroll
        for (int jj = 0; jj < 4; ++jj) o[jj] = valid ? (acc[i][jj] + bias) : 0.0f;
        *(float4*)(drow + (size_t)j * 192 + tx * 4) = make_float4(o[0], o[1], o[2], o[3]);
    }
}

__global__ void k_pack(const float* __restrict__ qslab, const float* __restrict__ kslab,
                       short* __restrict__ qpack, short* __restrict__ kpack) {
    const int kstep = blockIdx.x, b = blockIdx.y, tensor = blockIdx.z;
    const float* src = (tensor ? kslab : qslab) + (size_t)b * (CPAD * 192);
    short* dst = (tensor ? kpack : qpack) + (size_t)(b * KSTEPS + kstep) * PACK_BK;
    const int t = threadIdx.x;
    const int tile = t >> 6, lane = t & 63;
    const int hf = (lane >> 5) & 1, col = lane & 31;
    const int dbase = kstep * 16 + hf * 8;
    const int x = tile * 32 + col;

    short8 H, L;
#pragma unroll
    for (int e = 0; e < 8; ++e) {
        float v = src[(size_t)(dbase + e) * 192 + x];
        unsigned short h = f2bf(v);
        unsigned short l = f2bf(v - bf2f(h));
        H[e] = (short)h;
        L[e] = (short)l;
    }
    ((short8*)dst)[(0 * 6 + tile) * 64 + lane] = H;
    ((short8*)dst)[(1 * 6 + tile) * 64 + lane] = L;
}

__global__ __launch_bounds__(256, 2)
void k_corr(const short* __restrict__ qpack, const short* __restrict__ kpack,
            const float* __restrict__ sig, float* __restrict__ sc) {
    __shared__ short smem[2 * 12288];
    const int qk = blockIdx.x, q = qk >> 5, k = qk & 31;
    const int tid = threadIdx.x, lane = tid & 63, w = tid >> 6;
    const int ws = w >> 1, wt = w & 1;
    const char* Abase = (const char*)(kpack + (size_t)k * KSTEPS * PACK_BK);
    const char* Bbase = (const char*)(qpack + (size_t)q * KSTEPS * PACK_BK);

    f32x16 acc[3][3];
#pragma unroll
    for (int i = 0; i < 3; ++i)
#pragma unroll
        for (int j = 0; j < 3; ++j)
#pragma unroll
            for (int r = 0; r < 16; ++r) acc[i][j][r] = 0.0f;

    auto stage = [&](int buf, int ks) {
#pragma unroll
        for (int u = 0; u < 6; ++u) {
            int c = u * 4 + w;
            const char* g = (c < 12 ? Abase + (size_t)ks * 12288 + c * 1024
                                    : Bbase + (size_t)ks * 12288 + (c - 12) * 1024) + lane * 16;
            g2lds16(g, (char*)smem + buf * 24576 + c * 1024);
        }
    };

    stage(0, 0);
    __syncthreads();

    int buf = 0;
    for (int ks = 0; ks < KSTEPS; ++ks) {
        if (ks + 1 < KSTEPS) stage(buf ^ 1, ks + 1);

        const short8* LA = (const short8*)((const char*)smem + buf * 24576);
        const short8* LB = (const short8*)((const char*)smem + buf * 24576 + 12288);
        short8 Ah[3], Al[3], Bh[3], Bl[3];
#pragma unroll
        for (int u = 0; u < 3; ++u) {
            Ah[u] = LA[(0 * 6 + ws * 3 + u) * 64 + lane];
            Al[u] = LA[(1 * 6 + ws * 3 + u) * 64 + lane];
            Bh[u] = LB[(0 * 6 + wt * 3 + u) * 64 + lane];
            Bl[u] = LB[(1 * 6 + wt * 3 + u) * 64 + lane];
        }
#pragma unroll
        for (int i = 0; i < 3; ++i)
#pragma unroll
            for (int j = 0; j < 3; ++j) {
                acc[i][j] = __builtin_amdgcn_mfma_f32_32x32x16_bf16(Ah[i], Bh[j], acc[i][j], 0, 0, 0);
                acc[i][j] = __builtin_amdgcn_mfma_f32_32x32x16_bf16(Al[i], Bh[j], acc[i][j], 0, 0, 0);
                acc[i][j] = __builtin_amdgcn_mfma_f32_32x32x16_bf16(Ah[i], Bl[j], acc[i][j], 0, 0, 0);
            }
        __syncthreads();
        buf ^= 1;
    }

    const int col = lane & 31, hf = lane >> 5;
    float* scr = (float*)smem;
    float cm[3] = {-3.0e38f, -3.0e38f, -3.0e38f};
#pragma unroll
    for (int i = 0; i < 3; ++i) {
        const int sbase = (ws * 3 + i) * 32;
        float rv[16];
#pragma unroll
        for (int r = 0; r < 16; ++r) rv[r] = -3.0e38f;
#pragma unroll
        for (int j = 0; j < 3; ++j) {
            const int tb = (wt * 3 + j) * 32 + col;
#pragma unroll
            for (int r = 0; r < 16; ++r) {
                int row = (r & 3) + 8 * (r >> 2) + 4 * hf;
                float v = acc[i][j][r] * sig[(size_t)(sbase + row) * 192 + tb];
                rv[r] = fmaxf(rv[r], v);
                cm[j] = fmaxf(cm[j], v);
            }
        }
#pragma unroll
        for (int m = 1; m < 32; m <<= 1)
#pragma unroll
            for (int r = 0; r < 16; ++r) rv[r] = fmaxf(rv[r], __shfl_xor(rv[r], m));
#pragma unroll
        for (int r = 0; r < 16; ++r)
            if (col == r)
                scr[384 + wt * 192 + sbase + (r & 3) + 8 * (r >> 2) + 4 * hf] = rv[r];
    }
#pragma unroll
    for (int j = 0; j < 3; ++j) {
        float c2 = fmaxf(cm[j], __shfl_xor(cm[j], 32));
        if (hf == 0) scr[ws * 192 + (wt * 3 + j) * 32 + col] = c2;
    }
    __syncthreads();
    if (tid < 192) {
        sc[(size_t)(2 * qk) * 192 + tid]     = fmaxf(scr[tid], scr[192 + tid]);
        sc[(size_t)(2 * qk + 1) * 192 + tid] = fmaxf(scr[384 + tid], scr[384 + 192 + tid]);
    }
}

__global__ __launch_bounds__(256, 2)
void k_fc2(const float* __restrict__ sc, const float* __restrict__ w2, float* __restrict__ out2) {
    __shared__ float Ast[32 * 132];
    __shared__ float Bst[32 * 132];
    const int bm = blockIdx.x & 15, bn = blockIdx.x >> 4;
    const int r0 = bm * 128, c0 = bn * 128;
    const int tid = threadIdx.x, ty = tid >> 4, tx = tid & 15;
    const int r = tid >> 1, half = (tid & 1) * 16;

    float acc[8][8];
#pragma unroll
    for (int i = 0; i < 8; ++i)
#pragma unroll
        for (int j = 0; j < 8; ++j) acc[i][j] = 0.0f;

    for (int t0 = 0; t0 < 192; t0 += 32) {
        float4 av[4], bv[4];
        const float4* ga = (const float4*)(sc + (size_t)(r0 + r) * 192 + t0 + half);
        const float4* gb = (const float4*)(w2 + (size_t)(c0 + r) * 192 + t0 + half);
#pragma unroll
        for (int e = 0; e < 4; ++e) { av[e] = ga[e]; bv[e] = gb[e]; }
        __syncthreads();
#pragma unroll
        for (int e = 0; e < 4; ++e) {
            int t = half + 4 * e;
            Ast[(t + 0) * 132 + r] = av[e].x;  Bst[(t + 0) * 132 + r] = bv[e].x;
            Ast[(t + 1) * 132 + r] = av[e].y;  Bst[(t + 1) * 132 + r] = bv[e].y;
            Ast[(t + 2) * 132 + r] = av[e].z;  Bst[(t + 2) * 132 + r] = bv[e].z;
            Ast[(t + 3) * 132 + r] = av[e].w;  Bst[(t + 3) * 132 + r] = bv[e].w;
        }
        __syncthreads();
#pragma unroll 4
        for (int kk = 0; kk < 32; ++kk) {
            const float4* ap = (const float4*)(Ast + kk * 132 + ty * 8);
            const float4* bp = (const float4*)(Bst + kk * 132 + tx * 8);
            float4 A0 = ap[0], A1 = ap[1];
            float4 B0 = bp[0], B1 = bp[1];
            float a[8] = {A0.x, A0.y, A0.z, A0.w, A1.x, A1.y, A1.z, A1.w};
            float b[8] = {B0.x, B0.y, B0.z, B0.w, B1.x, B1.y, B1.z, B1.w};
#pragma unroll
            for (int i = 0; i < 8; ++i)
#pragma unroll
                for (int j = 0; j < 8; ++j)
                    acc[i][j] = fmaf(a[i], b[j], acc[i][j]);
        }
    }
#pragma unroll
    for (int i = 0; i < 8; ++i) {
        float4* op = (float4*)(out2 + (size_t)(r0 + ty * 8 + i) * 2048 + c0 + tx * 8);
        op[0] = make_float4(acc[i][0], acc[i][1], acc[i][2], acc[i][3]);
        op[1] = make_float4(acc[i][4], acc[i][5], acc[i][6], acc[i][7]);
    }
}

__global__ void k_colp(const float* __restrict__ out2, float* __restrict__ colp) {
    const int bc = blockIdx.x & 7, br = blockIdx.x >> 3;
    const int j = bc * 256 + threadIdx.x;
    float s = 0.0f, s2 = 0.0f;
    for (int rr = br * 64; rr < br * 64 + 64; ++rr) {
        float vv = out2[(size_t)rr * 2048 + j];
        s += vv; s2 += vv * vv;
    }
    colp[((size_t)br * 2048 + j) * 2 + 0] = s;
    colp[((size_t)br * 2048 + j) * 2 + 1] = s2;
}

__global__ void k_colf(const float* __restrict__ colp, float* __restrict__ m2r2) {
    const int j = blockIdx.x * 256 + threadIdx.x;
    if (j >= 2048) return;
    float s = 0.0f, s2 = 0.0f;
    for (int br = 0; br < 32; ++br) {
        s  += colp[((size_t)br * 2048 + j) * 2 + 0];
        s2 += colp[((size_t)br * 2048 + j) * 2 + 1];
    }
    float m = s * (1.0f / 2048.0f);
    float var = s2 * (1.0f / 2048.0f) - m * m;
    m2r2[j * 2 + 0] = m;
    m2r2[j * 2 + 1] = rsqrtf(var + EPS);
}

__global__ void k_fc3(const float* __restrict__ out2, const float* __restrict__ m2r2,
                      const float* __restrict__ w3, float* __restrict__ y) {
    const int rr = blockIdx.x;
    const int tid = threadIdx.x;
    __shared__ float red[4];
    float s = 0.0f;
    for (int j = tid; j < 2048; j += 256) {
        float2 mr = ((const float2*)m2r2)[j];
        float vv = (out2[(size_t)rr * 2048 + j] - mr.x) * mr.y;
        vv = fmaxf(vv, 0.0f);
        s += vv * w3[j];
    }
#pragma unroll
    for (int off = 32; off; off >>= 1) s += __shfl_xor(s, off);
    if ((tid & 63) == 0) red[tid >> 6] = s;
    __syncthreads();
    if (tid == 0) y[rr] = red[0] + red[1] + red[2] + red[3];
}

__global__ void k_bn3(const float* __restrict__ y, float* __restrict__ score, int first) {
    const int tid = threadIdx.x;
    __shared__ float rs[4], rs2[4];
    float p[4]; float s = 0.0f, s2 = 0.0f;
#pragma unroll
    for (int u = 0; u < 4; ++u) {
        int i = tid + (u << 8);
        float vv = y[2 * i] + y[2 * i + 1];
        p[u] = vv; s += vv; s2 += vv * vv;
    }
#pragma unroll
    for (int off = 32; off; off >>= 1) { s += __shfl_xor(s, off); s2 += __shfl_xor(s2, off); }
    if ((tid & 63) == 0) { rs[tid >> 6] = s; rs2[tid >> 6] = s2; }
    __syncthreads();
    float S = rs[0] + rs[1] + rs[2] + rs[3];
    float S2 = rs2[0] + rs2[1] + rs2[2] + rs2[3];
    float m = S * (1.0f / 1024.0f);
    float var = S2 * (1.0f / 1024.0f) - m * m;
    float rstd = rsqrtf(var + EPS);
#pragma unroll
    for (int u = 0; u < 4; ++u) {
        int i = tid + (u << 8);
        float vv = (p[u] - m) * rstd;
        score[i] = first ? vv : (score[i] + vv);
    }
}

__global__ void k_final(const float* __restrict__ score, float* __restrict__ out) {
    const int tid = threadIdx.x;
    __shared__ float rs[4], rs2[4];
    float p[4]; float s = 0.0f, s2 = 0.0f;
#pragma unroll
    for (int u = 0; u < 4; ++u) {
        int i = tid + (u << 8);
        float vv = score[i];
        p[u] = vv; s += vv; s2 += vv * vv;
    }
#pragma unroll
    for (int off = 32; off; off >>= 1) { s += __shfl_xor(s, off); s2 += __shfl_xor(s2, off); }
    if ((tid & 63) == 0) { rs[tid >> 6] = s; rs2[tid >> 6] = s2; }
    __syncthreads();
    float S = rs[0] + rs[1] + rs[2] + rs[3];
    float S2 = rs2[0] + rs2[1] + rs2[2] + rs2[3];
    float m = S * (1.0f / 1024.0f);
    float var = S2 * (1.0f / 1024.0f) - m * m;
    float rstd = rsqrtf(var + EPS);
#pragma unroll
    for (int u = 0; u < 4; ++u) {
        int i = tid + (u << 8);
        out[i] = (p[u] - m) * rstd;
    }
}

// ---------------- launch ----------------
extern "C" void kernel_launch(void* const* d_in, const int* in_sizes, int n_in,
                              void* d_out, int out_size, void* d_ws, size_t ws_size,
                              hipStream_t stream) {
    const float* gallery = (const float*)d_in[0];
    const float* query   = (const float*)d_in[1];
    float* ws = (float*)d_ws;

    const bool batched = (ws_size >= (size_t)B_TOTAL * sizeof(float));

    if (batched) {
        // ---- 10-dispatch 3-layer-batched pipeline (needs 58.3 MB ws) ----
        k_sigse<<<(3 * 36864 + 255) / 256, 256, 0, stream>>>(
            (const float*)d_in[2 + 0 * 7 + 2], (const float*)d_in[2 + 1 * 7 + 2],
            (const float*)d_in[2 + 2 * 7 + 2], ws + B_SIGSE);
        k_w1t_b<<<(3 * CPAD * CPAD + 255) / 256, 256, 0, stream>>>(
            (const float*)d_in[2 + 0 * 7 + 0], (const float*)d_in[2 + 1 * 7 + 0],
            (const float*)d_in[2 + 2 * 7 + 0], ws + B_W1T);
        k_fc1_b<<<dim3(3, 32, 6), 256, 0, stream>>>(
            gallery, query, ws + B_W1T,
            (const float*)d_in[2 + 0 * 7 + 1], (const float*)d_in[2 + 1 * 7 + 1],
            (const float*)d_in[2 + 2 * 7 + 1], ws + B_SLAB);
        k_pack_b<<<dim3(KSTEPS, 32, 6), 384, 0, stream>>>(ws + B_SLAB, (short*)(ws + B_PACKF));
        k_corr_b<<<dim3(1024, 3), 256, 0, stream>>>((const short*)(ws + B_PACKF),
                                                    ws + B_SIGSE, ws + B_SC);
        k_fc2c_b<<<dim3(256, 3), 256, 0, stream>>>(
            ws + B_SC,
            (const float*)d_in[2 + 0 * 7 + 3], (const float*)d_in[2 + 1 * 7 + 3],
            (const float*)d_in[2 + 2 * 7 + 3], ws + B_OUT2, ws + B_COLP);
        k_colf_b<<<24, 256, 0, stream>>>(ws + B_COLP, ws + B_M2R2);
        k_fc3_b<<<dim3(2048, 3), 256, 0, stream>>>(
            ws + B_OUT2, ws + B_M2R2,
            (const float*)d_in[2 + 0 * 7 + 5], (const float*)d_in[2 + 1 * 7 + 5],
            (const float*)d_in[2 + 2 * 7 + 5], ws + B_Y);
        k_bn3_b<<<3, 256, 0, stream>>>(ws + B_Y, ws + B_SC3);
        k_final3<<<1, 256, 0, stream>>>(ws + B_SC3, (float*)d_out);
        return;
    }

    // ---- fallback: proven per-layer pipeline (28.1 MB ws) ----
    const int cs[3] = {171, 171, 170};
    const int st[3] = {0, 171, 342};

    short* qpack = (short*)(ws + OFF_QPACK);
    short* kpack = (short*)(ws + OFF_KPACK);

    k_sigse<<<(3 * 36864 + 255) / 256, 256, 0, stream>>>(
        (const float*)d_in[2 + 0 * 7 + 2], (const float*)d_in[2 + 1 * 7 + 2],
        (const float*)d_in[2 + 2 * 7 + 2], ws + OFF_SIGSE);

    for (int l = 0; l < 3; ++l) {
        const float* w1 = (const float*)d_in[2 + l * 7 + 0];
        const float* b1 = (const float*)d_in[2 + l * 7 + 1];
        const float* w2 = (const float*)d_in[2 + l * 7 + 3];
        const float* w3 = (const float*)d_in[2 + l * 7 + 5];

        k_w1t<<<(CPAD * CPAD + 255) / 256, 256, 0, stream>>>(w1, cs[l], ws + OFF_W1T);
        k_fc1<<<dim3(3, 32, 2), 256, 0, stream>>>(gallery, query, ws + OFF_W1T, b1,
                                                  cs[l], st[l], ws + OFF_QSLAB, ws + OFF_KSLAB);
        k_pack<<<dim3(KSTEPS, 32, 2), 384, 0, stream>>>(ws + OFF_QSLAB, ws + OFF_KSLAB,
                                                        qpack, kpack);
        k_corr<<<1024, 256, 0, stream>>>(qpack, kpack, ws + OFF_SIGSE + l * 36864, ws + OFF_SC);
        k_fc2<<<256, 256, 0, stream>>>(ws + OFF_SC, w2, ws + OFF_OUT2);
        k_colp<<<256, 256, 0, stream>>>(ws + OFF_OUT2, ws + OFF_COLP);
        k_colf<<<8, 256, 0, stream>>>(ws + OFF_COLP, ws + OFF_M2V2);
        k_fc3<<<2048, 256, 0, stream>>>(ws + OFF_OUT2, ws + OFF_M2V2, w3, ws + OFF_Y);
        k_bn3<<<1, 256, 0, stream>>>(ws + OFF_Y, ws + OFF_SCORE, l == 0 ? 1 : 0);
    }
    k_final<<<1, 256, 0, stream>>>(ws + OFF_SCORE, (float*)d_out);
}

// Round 7
// 373.156 us; speedup vs baseline: 3.0908x; 1.0426x over previous
//
#include <hip/hip_runtime.h>
#include <math.h>

// ---------------- constants ----------------
#define EPS 1e-5f
#define TOTAL_IN (32*512*192)   // floats per input tensor (gallery/query)
#define CPAD 176                // K-pad: 171 -> 11*16 (11 MFMA k-steps)
#define MPAD 192                // fc1 M-pad: 176 -> 192 = 16*12 (vector A-reads)
#define KSTEPS 11
#define PACK_BK 6144            // shorts per (b,kstep): 2 planes * 6 tiles * 64 lanes * 8

// ======== fallback (per-layer) workspace offsets, floats (28.1 MB) ========
#define OFF_SIGSE 0u
#define OFF_W1T   110592u
#define OFF_QPACK 141568u
#define OFF_KPACK 1222912u
#define OFF_SC    2304256u
#define OFF_OUT2  2697472u
#define OFF_QSLAB OFF_OUT2
#define OFF_KSLAB (OFF_OUT2 + 1081344u)
#define OFF_COLP  6891776u
#define OFF_M2V2  7022848u
#define OFF_Y     7026944u
#define OFF_SCORE 7028992u

// ======== batched (3-layer) workspace offsets, floats (63.1 MB) ========
#define B_SIGSE 0u              // 110592
#define B_W1T   110592u         // 3*176*192 = 101376
#define B_SCPF  211968u         // sc packs: 3*786432 shorts = 1179648 floats
#define B_W2PF  1391616u        // w2 packs: 1179648 floats
#define B_COLP  2571264u        // 3*16*2048*2 = 196608
#define B_M2R2  2767872u        // 12288
#define B_Y     2780160u        // 6144
#define B_SC3   2786304u        // 3072
#define B_BIG   2789376u        // slabs(6488064)+packs(6488064) = 12976128; out2(12582912) overlays
#define B_SLAB  B_BIG
#define B_PACKF (B_BIG + 6488064u)
#define B_OUT2  B_BIG
#define B_TOTAL 15765504u       // floats = 63,062,016 bytes

typedef __attribute__((ext_vector_type(8)))  short short8;
typedef __attribute__((ext_vector_type(16))) float f32x16;

__device__ __forceinline__ unsigned short f2bf(float x) {
    unsigned u = __float_as_uint(x);
    u += 0x7fffu + ((u >> 16) & 1u);
    return (unsigned short)(u >> 16);
}
__device__ __forceinline__ float bf2f(unsigned short h) {
    return __uint_as_float(((unsigned)h) << 16);
}

__device__ __forceinline__ void g2lds16(const void* g, void* l) {
    __builtin_amdgcn_global_load_lds((const __attribute__((address_space(1))) unsigned int*)g,
                                     (__attribute__((address_space(3))) unsigned int*)l, 16, 0, 0);
}

// ---------------- shared tiny kernel ----------------
__global__ void k_sigse(const float* __restrict__ se0, const float* __restrict__ se1,
                        const float* __restrict__ se2, float* __restrict__ dst) {
    int idx = blockIdx.x * 256 + threadIdx.x;
    if (idx >= 3 * 36864) return;
    int l = idx / 36864, r = idx % 36864;
    const float* se = (l == 0) ? se0 : ((l == 1) ? se1 : se2);
    float x = se[r];
    dst[idx] = 1.0f / (1.0f + __expf(-x));
}

// ================================================================
//                      BATCHED (3-layer) PATH
// ================================================================

// w1t[l][i][j] (M-padded): [176 k][192 j]
__global__ void k_w1t_b(const float* __restrict__ w1_0, const float* __restrict__ w1_1,
                        const float* __restrict__ w1_2, float* __restrict__ w1t) {
    int idx = blockIdx.x * 256 + threadIdx.x;
    if (idx >= 3 * CPAD * MPAD) return;
    int l = idx / (CPAD * MPAD), r = idx % (CPAD * MPAD);
    int i = r / MPAD, j = r % MPAD;
    int c = (l == 2) ? 170 : 171;
    const float* w1 = (l == 0) ? w1_0 : ((l == 1) ? w1_1 : w1_2);
    w1t[idx] = (i < c && j < c) ? w1[j * c + i] : 0.0f;
}

// fc1 batched, vectorized A-reads: grid (3 quad, 32 b, 6=l*2+tensor)
__global__ __launch_bounds__(256, 4)
void k_fc1_b(const float* __restrict__ g0, const float* __restrict__ g1,
             const float* __restrict__ w1tb,
             const float* __restrict__ b1_0, const float* __restrict__ b1_1,
             const float* __restrict__ b1_2, float* __restrict__ slabs) {
    __shared__ float As[2 * 16 * MPAD];   // [16][192] per buf
    __shared__ float Bs[2 * 16 * 64];
    const int quad = blockIdx.x, b = blockIdx.y, z = blockIdx.z;
    const int l = z >> 1, tensor = z & 1;
    const int c = (l == 2) ? 170 : 171, st = l * 171;
    const float* inp = tensor ? g1 : g0;
    const float* w1t = w1tb + (unsigned)l * (CPAD * MPAD);
    const float* b1 = (l == 0) ? b1_0 : ((l == 1) ? b1_1 : b1_2);
    float* dst = slabs + (size_t)z * 1081344u;
    const int tid = threadIdx.x, ty = tid >> 4, tx = tid & 15;
    const size_t boff = (size_t)b * 98304 + (size_t)st * 192 + (size_t)quad * 64;

    float acc[12][4];
#pragma unroll
    for (int i = 0; i < 12; ++i)
#pragma unroll
        for (int j = 0; j < 4; ++j) acc[i][j] = 0.0f;

    // staging: A 768 float4, B 256 float4 => 1024 = 4/thread exactly
    float4 v[4];
    auto load_chunk = [&](int ci) {
#pragma unroll
        for (int e = 0; e < 4; ++e) {
            int f = tid + (e << 8);
            if (f < 768) {
                v[e] = *(const float4*)(w1t + ci * 3072 + f * 4);
            } else {
                int f2 = f - 768;                 // 0..255
                int r = f2 >> 4, c4 = f2 & 15;
                size_t off = boff + (size_t)(ci * 16 + r) * 192 + c4 * 4;
                if (off > (size_t)(TOTAL_IN - 4)) off = (size_t)(TOTAL_IN - 4); // layer-2 tail clamp (A rows are 0 there)
                v[e] = *(const float4*)(inp + off);
            }
        }
    };
    auto write_chunk = [&](int buf) {
        float* Ad = As + buf * 3072;
        float* Bd = Bs + buf * 1024;
#pragma unroll
        for (int e = 0; e < 4; ++e) {
            int f = tid + (e << 8);
            if (f < 768) *(float4*)(Ad + f * 4) = v[e];
            else         *(float4*)(Bd + (f - 768) * 4) = v[e];
        }
    };

    load_chunk(0); write_chunk(0);
    __syncthreads();

    for (int ci = 0; ci < 11; ++ci) {
        const int buf = ci & 1;
        const bool pf = (ci + 1 < 11);
        if (pf) load_chunk(ci + 1);

        const float* Aw = As + buf * 3072 + ty * 12;
        const float* Bw = Bs + buf * 1024 + tx * 4;
#pragma unroll 2
        for (int kk = 0; kk < 16; ++kk) {
            const float4* ap = (const float4*)(Aw + kk * MPAD);
            float4 A0 = ap[0], A1 = ap[1], A2 = ap[2];
            float a[12] = {A0.x, A0.y, A0.z, A0.w, A1.x, A1.y, A1.z, A1.w, A2.x, A2.y, A2.z, A2.w};
            float4 B0 = *(const float4*)(Bw + kk * 64);
            float bb[4] = {B0.x, B0.y, B0.z, B0.w};
#pragma unroll
            for (int i = 0; i < 12; ++i)
#pragma unroll
                for (int j = 0; j < 4; ++j)
                    acc[i][j] = fmaf(a[i], bb[j], acc[i][j]);
        }
        if (pf) write_chunk(buf ^ 1);
        __syncthreads();
    }

    float* drow = dst + (size_t)b * (CPAD * 192) + quad * 64;
#pragma unroll
    for (int i = 0; i < 12; ++i) {
        int j = ty * 12 + i;
        if (j >= CPAD) continue;          // rows 176..191 not stored
        bool valid = (j < c);
        float bias = valid ? b1[j] : 0.0f;
        float o[4];
#pragma unroll
        for (int jj = 0; jj < 4; ++jj) o[jj] = valid ? (acc[i][jj] + bias) : 0.0f;
        *(float4*)(drow + (size_t)j * 192 + tx * 4) = make_float4(o[0], o[1], o[2], o[3]);
    }
}

// pack batched: grid (11, 32, 6)
__global__ void k_pack_b(const float* __restrict__ slabs, short* __restrict__ packs) {
    const int kstep = blockIdx.x, b = blockIdx.y, z = blockIdx.z;
    const float* src = slabs + (size_t)z * 1081344u + (size_t)b * (CPAD * 192);
    short* dst = packs + (size_t)z * 2162688u + (size_t)(b * KSTEPS + kstep) * PACK_BK;
    const int t = threadIdx.x;              // 0..383
    const int tile = t >> 6, lane = t & 63;
    const int hf = (lane >> 5) & 1, col = lane & 31;
    const int dbase = kstep * 16 + hf * 8;
    const int x = tile * 32 + col;

    short8 H, L;
#pragma unroll
    for (int e = 0; e < 8; ++e) {
        float v = src[(size_t)(dbase + e) * 192 + x];
        unsigned short h = f2bf(v);
        unsigned short l = f2bf(v - bf2f(h));
        H[e] = (short)h;
        L[e] = (short)l;
    }
    ((short8*)dst)[(0 * 6 + tile) * 64 + lane] = H;
    ((short8*)dst)[(1 * 6 + tile) * 64 + lane] = L;
}

// w2 -> B-fragment hi/lo pack: grid (64 jtiles, 3 l), 256 thr
__global__ void k_w2p(const float* __restrict__ w2_0, const float* __restrict__ w2_1,
                      const float* __restrict__ w2_2, short* __restrict__ w2p) {
    const int jt = blockIdx.x, l = blockIdx.y;
    const float* w2 = (l == 0) ? w2_0 : ((l == 1) ? w2_1 : w2_2);
    short* WP = w2p + (size_t)l * 786432u;
    const int tid = threadIdx.x, lane = tid & 63, sub = tid >> 6;
    const int j = jt * 32 + (lane & 31), hf = lane >> 5;
#pragma unroll
    for (int kk = 0; kk < 3; ++kk) {
        int ks = sub * 3 + kk;
        const float4* src = (const float4*)(w2 + (size_t)j * 192 + ks * 16 + hf * 8);
        float4 a = src[0], b = src[1];
        float v[8] = {a.x, a.y, a.z, a.w, b.x, b.y, b.z, b.w};
        short8 H, L;
#pragma unroll
        for (int e = 0; e < 8; ++e) {
            unsigned short h = f2bf(v[e]);
            H[e] = (short)h;
            L[e] = (short)f2bf(v[e] - bf2f(h));
        }
        ((short8*)WP)[((jt * 12 + ks) * 2 + 0) * 64 + lane] = H;
        ((short8*)WP)[((jt * 12 + ks) * 2 + 1) * 64 + lane] = L;
    }
}

// corr batched: grid (1024, 3); epilogue emits sc as fc2 A-fragments (hi/lo)
__global__ __launch_bounds__(256, 2)
void k_corr_b(const short* __restrict__ packs, const float* __restrict__ sigb,
              short* __restrict__ scp) {
    __shared__ short smem[2 * 12288];
    const int qk = blockIdx.x, l = blockIdx.y;
    const int q = qk >> 5, k = qk & 31;
    const int tid = threadIdx.x, lane = tid & 63, w = tid >> 6;
    const int ws = w >> 1, wt = w & 1;
    const short* qpack = packs + (size_t)(l * 2 + 0) * 2162688u;
    const short* kpack = packs + (size_t)(l * 2 + 1) * 2162688u;
    const float* sig = sigb + (unsigned)l * 36864u;
    short* scpl = scp + (size_t)l * 786432u;
    const char* Abase = (const char*)(kpack + (size_t)k * KSTEPS * PACK_BK);
    const char* Bbase = (const char*)(qpack + (size_t)q * KSTEPS * PACK_BK);

    f32x16 acc[3][3];
#pragma unroll
    for (int i = 0; i < 3; ++i)
#pragma unroll
        for (int j = 0; j < 3; ++j)
#pragma unroll
            for (int r = 0; r < 16; ++r) acc[i][j][r] = 0.0f;

    auto stage = [&](int buf, int ks) {
#pragma unroll
        for (int u = 0; u < 6; ++u) {
            int c = u * 4 + w;
            const char* g = (c < 12 ? Abase + (size_t)ks * 12288 + c * 1024
                                    : Bbase + (size_t)ks * 12288 + (c - 12) * 1024) + lane * 16;
            g2lds16(g, (char*)smem + buf * 24576 + c * 1024);
        }
    };

    stage(0, 0);
    __syncthreads();

    int buf = 0;
    for (int ks = 0; ks < KSTEPS; ++ks) {
        if (ks + 1 < KSTEPS) stage(buf ^ 1, ks + 1);

        const short8* LA = (const short8*)((const char*)smem + buf * 24576);
        const short8* LB = (const short8*)((const char*)smem + buf * 24576 + 12288);
        short8 Ah[3], Al[3], Bh[3], Bl[3];
#pragma unroll
        for (int u = 0; u < 3; ++u) {
            Ah[u] = LA[(0 * 6 + ws * 3 + u) * 64 + lane];
            Al[u] = LA[(1 * 6 + ws * 3 + u) * 64 + lane];
            Bh[u] = LB[(0 * 6 + wt * 3 + u) * 64 + lane];
            Bl[u] = LB[(1 * 6 + wt * 3 + u) * 64 + lane];
        }
#pragma unroll
        for (int i = 0; i < 3; ++i)
#pragma unroll
            for (int j = 0; j < 3; ++j) {
                acc[i][j] = __builtin_amdgcn_mfma_f32_32x32x16_bf16(Ah[i], Bh[j], acc[i][j], 0, 0, 0);
                acc[i][j] = __builtin_amdgcn_mfma_f32_32x32x16_bf16(Al[i], Bh[j], acc[i][j], 0, 0, 0);
                acc[i][j] = __builtin_amdgcn_mfma_f32_32x32x16_bf16(Ah[i], Bl[j], acc[i][j], 0, 0, 0);
            }
        __syncthreads();
        buf ^= 1;
    }

    const int col = lane & 31, hf = lane >> 5;
    float* scr = (float*)smem;
    float cm[3] = {-3.0e38f, -3.0e38f, -3.0e38f};
#pragma unroll
    for (int i = 0; i < 3; ++i) {
        const int sbase = (ws * 3 + i) * 32;
        float rv[16];
#pragma unroll
        for (int r = 0; r < 16; ++r) rv[r] = -3.0e38f;
#pragma unroll
        for (int j = 0; j < 3; ++j) {
            const int tb = (wt * 3 + j) * 32 + col;
#pragma unroll
            for (int r = 0; r < 16; ++r) {
                int row = (r & 3) + 8 * (r >> 2) + 4 * hf;
                float v = acc[i][j][r] * sig[(size_t)(sbase + row) * 192 + tb];
                rv[r] = fmaxf(rv[r], v);
                cm[j] = fmaxf(cm[j], v);
            }
        }
#pragma unroll
        for (int m = 1; m < 32; m <<= 1)
#pragma unroll
            for (int r = 0; r < 16; ++r) rv[r] = fmaxf(rv[r], __shfl_xor(rv[r], m));
#pragma unroll
        for (int r = 0; r < 16; ++r)
            if (col == r)
                scr[384 + wt * 192 + sbase + (r & 3) + 8 * (r >> 2) + 4 * hf] = rv[r];
    }
#pragma unroll
    for (int j = 0; j < 3; ++j) {
        float c2 = fmaxf(cm[j], __shfl_xor(cm[j], 32));
        if (hf == 0) scr[ws * 192 + (wt * 3 + j) * 32 + col] = c2;
    }
    __syncthreads();
    // pack rows 2qk (per-t max) and 2qk+1 (per-s max) as fc2 A-fragments
    if (tid < 96) {
        const int row = tid / 48, rem = tid % 48;
        const int ks2 = rem >> 2, hf2 = (rem >> 1) & 1, pl = rem & 1;
        const int r = 2 * qk + row;
        const float* s0 = scr + row * 384;
        short8 o;
#pragma unroll
        for (int e = 0; e < 8; ++e) {
            int t = ks2 * 16 + hf2 * 8 + e;
            float v = fmaxf(s0[t], s0[192 + t]);
            unsigned short h = f2bf(v);
            o[e] = pl ? (short)f2bf(v - bf2f(h)) : (short)h;
        }
        ((short8*)scpl)[(((r >> 5) * 12 + ks2) * 2 + pl) * 64 + (hf2 * 32 + (r & 31))] = o;
    }
}

// fc2 MFMA (split-bf16) + fused BN2 column partials: grid (256, 3)
__global__ __launch_bounds__(256, 2)
void k_fc2m_b(const short* __restrict__ scp, const short* __restrict__ w2p,
              float* __restrict__ out2b, float* __restrict__ colpb) {
    __shared__ short smem[2 * 8192];   // per buf 16KB: A 8x1KB | B 8x1KB
    const int rblk = blockIdx.x & 15, nblk = blockIdx.x >> 4, l = blockIdx.y;
    float* out2 = out2b + (size_t)l * 4194304u;
    float* colp = colpb + (size_t)l * 65536u;
    const int tid = threadIdx.x, lane = tid & 63, w = tid >> 6;
    const int wr = w >> 1, wc = w & 1;
    const char* SPb = (const char*)(scp + (size_t)l * 786432u + (size_t)rblk * 4 * 12288u);
    const char* WPb = (const char*)(w2p + (size_t)l * 786432u + (size_t)nblk * 4 * 12288u);

    f32x16 acc[2][2];
#pragma unroll
    for (int i = 0; i < 2; ++i)
#pragma unroll
        for (int j = 0; j < 2; ++j)
#pragma unroll
            for (int r = 0; r < 16; ++r) acc[i][j][r] = 0.0f;

    auto stage = [&](int buf, int ks) {
#pragma unroll
        for (int u = 0; u < 4; ++u) {
            int c = u * 4 + w;   // wave-uniform, 16 chunks of 1KB
            const char* g = (c < 8 ? SPb + (c >> 1) * 24576 + ks * 2048 + (c & 1) * 1024
                                   : WPb + ((c - 8) >> 1) * 24576 + ks * 2048 + (c & 1) * 1024) + lane * 16;
            g2lds16(g, (char*)smem + buf * 16384 + c * 1024);
        }
    };

    stage(0, 0);
    __syncthreads();

    int buf = 0;
    for (int ks = 0; ks < 12; ++ks) {
        if (ks + 1 < 12) stage(buf ^ 1, ks + 1);

        const char* base = (const char*)smem + buf * 16384;
        short8 Ah[2], Al[2], Bh[2], Bl[2];
#pragma unroll
        for (int mt = 0; mt < 2; ++mt) {
            Ah[mt] = *(const short8*)(base + ((wr * 2 + mt) * 2 + 0) * 1024 + lane * 16);
            Al[mt] = *(const short8*)(base + ((wr * 2 + mt) * 2 + 1) * 1024 + lane * 16);
        }
#pragma unroll
        for (int nt = 0; nt < 2; ++nt) {
            Bh[nt] = *(const short8*)(base + 8192 + ((wc * 2 + nt) * 2 + 0) * 1024 + lane * 16);
            Bl[nt] = *(const short8*)(base + 8192 + ((wc * 2 + nt) * 2 + 1) * 1024 + lane * 16);
        }
#pragma unroll
        for (int mt = 0; mt < 2; ++mt)
#pragma unroll
            for (int nt = 0; nt < 2; ++nt) {
                acc[mt][nt] = __builtin_amdgcn_mfma_f32_32x32x16_bf16(Ah[mt], Bh[nt], acc[mt][nt], 0, 0, 0);
                acc[mt][nt] = __builtin_amdgcn_mfma_f32_32x32x16_bf16(Al[mt], Bh[nt], acc[mt][nt], 0, 0, 0);
                acc[mt][nt] = __builtin_amdgcn_mfma_f32_32x32x16_bf16(Ah[mt], Bl[nt], acc[mt][nt], 0, 0, 0);
            }
        __syncthreads();
        buf ^= 1;
    }

    // C store (out2 fp32) + fused column partials
    const int hf = lane >> 5, cl = lane & 31;
#pragma unroll
    for (int mt = 0; mt < 2; ++mt)
#pragma unroll
        for (int nt = 0; nt < 2; ++nt) {
            const int c0 = nblk * 128 + (wc * 2 + nt) * 32 + cl;
#pragma unroll
            for (int r = 0; r < 16; ++r) {
                int row = rblk * 128 + (wr * 2 + mt) * 32 + (r & 3) + 8 * (r >> 2) + 4 * hf;
                out2[(size_t)row * 2048 + c0] = acc[mt][nt][r];
            }
        }
    float* cs = (float*)smem;        // [128 cols][4 contributors]
    float* cq = cs + 512;
#pragma unroll
    for (int nt = 0; nt < 2; ++nt) {
        float s = 0.0f, q2 = 0.0f;
#pragma unroll
        for (int mt = 0; mt < 2; ++mt)
#pragma unroll
            for (int r = 0; r < 16; ++r) { float v = acc[mt][nt][r]; s += v; q2 += v * v; }
        int ci = (wc * 2 + nt) * 32 + cl;
        cs[ci * 4 + wr * 2 + hf] = s;
        cq[ci * 4 + wr * 2 + hf] = q2;
    }
    __syncthreads();
    if (tid < 128) {
        float s = 0.0f, q2 = 0.0f;
#pragma unroll
        for (int u = 0; u < 4; ++u) { s += cs[tid * 4 + u]; q2 += cq[tid * 4 + u]; }
        colp[((size_t)rblk * 2048 + nblk * 128 + tid) * 2 + 0] = s;
        colp[((size_t)rblk * 2048 + nblk * 128 + tid) * 2 + 1] = q2;
    }
}

// reduce 16 row-block partials -> mean/rstd per (l, j). grid 24
__global__ void k_colf_b(const float* __restrict__ colpb, float* __restrict__ m2r2b) {
    const int idx = blockIdx.x * 256 + threadIdx.x;
    if (idx >= 3 * 2048) return;
    const int l = idx >> 11, j = idx & 2047;
    const float* colp = colpb + (size_t)l * 65536u;
    float s = 0.0f, s2 = 0.0f;
    for (int bm = 0; bm < 16; ++bm) {
        s  += colp[((size_t)bm * 2048 + j) * 2 + 0];
        s2 += colp[((size_t)bm * 2048 + j) * 2 + 1];
    }
    float m = s * (1.0f / 2048.0f);
    float var = s2 * (1.0f / 2048.0f) - m * m;
    m2r2b[(size_t)l * 4096 + j * 2 + 0] = m;
    m2r2b[(size_t)l * 4096 + j * 2 + 1] = rsqrtf(var + EPS);
}

// fused BN2+relu+fc3: grid (2048, 3)
__global__ void k_fc3_b(const float* __restrict__ out2b, const float* __restrict__ m2r2b,
                        const float* __restrict__ w3_0, const float* __restrict__ w3_1,
                        const float* __restrict__ w3_2, float* __restrict__ yb) {
    const int rr = blockIdx.x, l = blockIdx.y;
    const float* out2 = out2b + (size_t)l * 4194304u;
    const float* m2r2 = m2r2b + (size_t)l * 4096u;
    const float* w3 = (l == 0) ? w3_0 : ((l == 1) ? w3_1 : w3_2);
    const int tid = threadIdx.x;
    __shared__ float red[4];
    float s = 0.0f;
    for (int j = tid; j < 2048; j += 256) {
        float2 mr = ((const float2*)m2r2)[j];
        float vv = (out2[(size_t)rr * 2048 + j] - mr.x) * mr.y;
        vv = fmaxf(vv, 0.0f);
        s += vv * w3[j];
    }
#pragma unroll
    for (int off = 32; off; off >>= 1) s += __shfl_xor(s, off);
    if ((tid & 63) == 0) red[tid >> 6] = s;
    __syncthreads();
    if (tid == 0) yb[(size_t)l * 2048 + rr] = red[0] + red[1] + red[2] + red[3];
}

// pair-sum + BN3 per layer: grid 3
__global__ void k_bn3_b(const float* __restrict__ yb, float* __restrict__ sc3) {
    const int l = blockIdx.x, tid = threadIdx.x;
    const float* y = yb + (size_t)l * 2048u;
    __shared__ float rs[4], rs2[4];
    float p[4]; float s = 0.0f, s2 = 0.0f;
#pragma unroll
    for (int u = 0; u < 4; ++u) {
        int i = tid + (u << 8);
        float vv = y[2 * i] + y[2 * i + 1];
        p[u] = vv; s += vv; s2 += vv * vv;
    }
#pragma unroll
    for (int off = 32; off; off >>= 1) { s += __shfl_xor(s, off); s2 += __shfl_xor(s2, off); }
    if ((tid & 63) == 0) { rs[tid >> 6] = s; rs2[tid >> 6] = s2; }
    __syncthreads();
    float S = rs[0] + rs[1] + rs[2] + rs[3];
    float S2 = rs2[0] + rs2[1] + rs2[2] + rs2[3];
    float m = S * (1.0f / 1024.0f);
    float var = S2 * (1.0f / 1024.0f) - m * m;
    float rstd = rsqrtf(var + EPS);
#pragma unroll
    for (int u = 0; u < 4; ++u) {
        int i = tid + (u << 8);
        sc3[(size_t)l * 1024 + i] = (p[u] - m) * rstd;
    }
}

// sum 3 layers + final BN
__global__ void k_final3(const float* __restrict__ sc3, float* __restrict__ out) {
    const int tid = threadIdx.x;
    __shared__ float rs[4], rs2[4];
    float p[4]; float s = 0.0f, s2 = 0.0f;
#pragma unroll
    for (int u = 0; u < 4; ++u) {
        int i = tid + (u << 8);
        float vv = sc3[i] + sc3[1024 + i] + sc3[2048 + i];
        p[u] = vv; s += vv; s2 += vv * vv;
    }
#pragma unroll
    for (int off = 32; off; off >>= 1) { s += __shfl_xor(s, off); s2 += __shfl_xor(s2, off); }
    if ((tid & 63) == 0) { rs[tid >> 6] = s; rs2[tid >> 6] = s2; }
    __syncthreads();
    float S = rs[0] + rs[1] + rs[2] + rs[3];
    float S2 = rs2[0] + rs2[1] + rs2[2] + rs2[3];
    float m = S * (1.0f / 1024.0f);
    float var = S2 * (1.0f / 1024.0f) - m * m;
    float rstd = rsqrtf(var + EPS);
#pragma unroll
    for (int u = 0; u < 4; ++u) {
        int i = tid + (u << 8);
        out[i] = (p[u] - m) * rstd;
    }
}

// ================================================================
//              FALLBACK (per-layer) PATH — proven R5 code
// ================================================================

__global__ void k_w1t(const float* __restrict__ w1, int c, float* __restrict__ w1t) {
    int idx = blockIdx.x * 256 + threadIdx.x;
    if (idx >= CPAD * CPAD) return;
    int i = idx / CPAD, j = idx % CPAD;
    w1t[idx] = (i < c && j < c) ? w1[j * c + i] : 0.0f;
}

__global__ __launch_bounds__(256, 4)
void k_fc1(const float* __restrict__ g0, const float* __restrict__ g1,
           const float* __restrict__ w1t, const float* __restrict__ b1,
           int c, int st, float* __restrict__ d0, float* __restrict__ d1) {
    __shared__ float As[2 * 16 * CPAD];
    __shared__ float Bs[2 * 16 * 64];
    const int quad = blockIdx.x, b = blockIdx.y, tensor = blockIdx.z;
    const float* inp = tensor ? g1 : g0;
    float* dst = tensor ? d1 : d0;
    const int tid = threadIdx.x, ty = tid >> 4, tx = tid & 15;
    const size_t boff = (size_t)b * 98304 + (size_t)st * 192 + (size_t)quad * 64;

    float acc[11][4];
#pragma unroll
    for (int i = 0; i < 11; ++i)
#pragma unroll
        for (int j = 0; j < 4; ++j) acc[i][j] = 0.0f;

    float4 v[4];
    auto load_chunk = [&](int ci) {
#pragma unroll
        for (int e = 0; e < 4; ++e) {
            int f = tid + (e << 8);
            if (f < 704) {
                v[e] = *(const float4*)(w1t + ci * 2816 + f * 4);
            } else if (f < 960) {
                int f2 = f - 704;
                int r = f2 >> 4, c4 = f2 & 15;
                size_t off = boff + (size_t)(ci * 16 + r) * 192 + c4 * 4;
                if (off > (size_t)(TOTAL_IN - 4)) off = (size_t)(TOTAL_IN - 4);
                v[e] = *(const float4*)(inp + off);
            }
        }
    };
    auto write_chunk = [&](int buf) {
        float* Ad = As + buf * 2816;
        float* Bd = Bs + buf * 1024;
#pragma unroll
        for (int e = 0; e < 4; ++e) {
            int f = tid + (e << 8);
            if (f < 704)      *(float4*)(Ad + f * 4) = v[e];
            else if (f < 960) *(float4*)(Bd + (f - 704) * 4) = v[e];
        }
    };

    load_chunk(0); write_chunk(0);
    __syncthreads();

    for (int ci = 0; ci < 11; ++ci) {
        const int buf = ci & 1;
        const bool pf = (ci + 1 < 11);
        if (pf) load_chunk(ci + 1);

        const float* Aw = As + buf * 2816 + ty * 11;
        const float* Bw = Bs + buf * 1024 + tx * 4;
#pragma unroll 2
        for (int kk = 0; kk < 16; ++kk) {
            float a[11];
#pragma unroll
            for (int i = 0; i < 11; ++i) a[i] = Aw[kk * CPAD + i];
            float4 B0 = *(const float4*)(Bw + kk * 64);
            float bb[4] = {B0.x, B0.y, B0.z, B0.w};
#pragma unroll
            for (int i = 0; i < 11; ++i)
#pragma unroll
                for (int j = 0; j < 4; ++j)
                    acc[i][j] = fmaf(a[i], bb[j], acc[i][j]);
        }
        if (pf) write_chunk(buf ^ 1);
        __syncthreads();
    }

    float* drow = dst + (size_t)b * (CPAD * 192) + quad * 64;
#pragma unroll
    for (int i = 0; i < 11; ++i) {
        int j = ty * 11 + i;
        bool valid = (j < c);
        float bias = valid ? b1[j] : 0.0f;
        float o[4];
#pragma unroll
        for (int jj = 0; jj < 4; ++jj) o[jj] = valid ? (acc[i][jj] + bias) : 0.0f;
        *(float4*)(drow + (size_t)j * 192 + tx * 4) = make_float4(o[0], o[1], o[2], o[3]);
    }
}

__global__ void k_pack(const float* __restrict__ qslab, const float* __restrict__ kslab,
                       short* __restrict__ qpack, short* __restrict__ kpack) {
    const int kstep = blockIdx.x, b = blockIdx.y, tensor = blockIdx.z;
    const float* src = (tensor ? kslab : qslab) + (size_t)b * (CPAD * 192);
    short* dst = (tensor ? kpack : qpack) + (size_t)(b * KSTEPS + kstep) * PACK_BK;
    const int t = threadIdx.x;
    const int tile = t >> 6, lane = t & 63;
    const int hf = (lane >> 5) & 1, col = lane & 31;
    const int dbase = kstep * 16 + hf * 8;
    const int x = tile * 32 + col;

    short8 H, L;
#pragma unroll
    for (int e = 0; e < 8; ++e) {
        float v = src[(size_t)(dbase + e) * 192 + x];
        unsigned short h = f2bf(v);
        unsigned short l = f2bf(v - bf2f(h));
        H[e] = (short)h;
        L[e] = (short)l;
    }
    ((short8*)dst)[(0 * 6 + tile) * 64 + lane] = H;
    ((short8*)dst)[(1 * 6 + tile) * 64 + lane] = L;
}

__global__ __launch_bounds__(256, 2)
void k_corr(const short* __restrict__ qpack, const short* __restrict__ kpack,
            const float* __restrict__ sig, float* __restrict__ sc) {
    __shared__ short smem[2 * 12288];
    const int qk = blockIdx.x, q = qk >> 5, k = qk & 31;
    const int tid = threadIdx.x, lane = tid & 63, w = tid >> 6;
    const int ws = w >> 1, wt = w & 1;
    const char* Abase = (const char*)(kpack + (size_t)k * KSTEPS * PACK_BK);
    const char* Bbase = (const char*)(qpack + (size_t)q * KSTEPS * PACK_BK);

    f32x16 acc[3][3];
#pragma unroll
    for (int i = 0; i < 3; ++i)
#pragma unroll
        for (int j = 0; j < 3; ++j)
#pragma unroll
            for (int r = 0; r < 16; ++r) acc[i][j][r] = 0.0f;

    auto stage = [&](int buf, int ks) {
#pragma unroll
        for (int u = 0; u < 6; ++u) {
            int c = u * 4 + w;
            const char* g = (c < 12 ? Abase + (size_t)ks * 12288 + c * 1024
                                    : Bbase + (size_t)ks * 12288 + (c - 12) * 1024) + lane * 16;
            g2lds16(g, (char*)smem + buf * 24576 + c * 1024);
        }
    };

    stage(0, 0);
    __syncthreads();

    int buf = 0;
    for (int ks = 0; ks < KSTEPS; ++ks) {
        if (ks + 1 < KSTEPS) stage(buf ^ 1, ks + 1);

        const short8* LA = (const short8*)((const char*)smem + buf * 24576);
        const short8* LB = (const short8*)((const char*)smem + buf * 24576 + 12288);
        short8 Ah[3], Al[3], Bh[3], Bl[3];
#pragma unroll
        for (int u = 0; u < 3; ++u) {
            Ah[u] = LA[(0 * 6 + ws * 3 + u) * 64 + lane];
            Al[u] = LA[(1 * 6 + ws * 3 + u) * 64 + lane];
            Bh[u] = LB[(0 * 6 + wt * 3 + u) * 64 + lane];
            Bl[u] = LB[(1 * 6 + wt * 3 + u) * 64 + lane];
        }
#pragma unroll
        for (int i = 0; i < 3; ++i)
#pragma unroll
            for (int j = 0; j < 3; ++j) {
                acc[i][j] = __builtin_amdgcn_mfma_f32_32x32x16_bf16(Ah[i], Bh[j], acc[i][j], 0, 0, 0);
                acc[i][j] = __builtin_amdgcn_mfma_f32_32x32x16_bf16(Al[i], Bh[j], acc[i][j], 0, 0, 0);
                acc[i][j] = __builtin_amdgcn_mfma_f32_32x32x16_bf16(Ah[i], Bl[j], acc[i][j], 0, 0, 0);
            }
        __syncthreads();
        buf ^= 1;
    }

    const int col = lane & 31, hf = lane >> 5;
    float* scr = (float*)smem;
    float cm[3] = {-3.0e38f, -3.0e38f, -3.0e38f};
#pragma unroll
    for (int i = 0; i < 3; ++i) {
        const int sbase = (ws * 3 + i) * 32;
        float rv[16];
#pragma unroll
        for (int r = 0; r < 16; ++r) rv[r] = -3.0e38f;
#pragma unroll
        for (int j = 0; j < 3; ++j) {
            const int tb = (wt * 3 + j) * 32 + col;
#pragma unroll
            for (int r = 0; r < 16; ++r) {
                int row = (r & 3) + 8 * (r >> 2) + 4 * hf;
                float v = acc[i][j][r] * sig[(size_t)(sbase + row) * 192 + tb];
                rv[r] = fmaxf(rv[r], v);
                cm[j] = fmaxf(cm[j], v);
            }
        }
#pragma unroll
        for (int m = 1; m < 32; m <<= 1)
#pragma unroll
            for (int r = 0; r < 16; ++r) rv[r] = fmaxf(rv[r], __shfl_xor(rv[r], m));
#pragma unroll
        for (int r = 0; r < 16; ++r)
            if (col == r)
                scr[384 + wt * 192 + sbase + (r & 3) + 8 * (r >> 2) + 4 * hf] = rv[r];
    }
#pragma unroll
    for (int j = 0; j < 3; ++j) {
        float c2 = fmaxf(cm[j], __shfl_xor(cm[j], 32));
        if (hf == 0) scr[ws * 192 + (wt * 3 + j) * 32 + col] = c2;
    }
    __syncthreads();
    if (tid < 192) {
        sc[(size_t)(2 * qk) * 192 + tid]     = fmaxf(scr[tid], scr[192 + tid]);
        sc[(size_t)(2 * qk + 1) * 192 + tid] = fmaxf(scr[384 + tid], scr[384 + 192 + tid]);
    }
}

__global__ __launch_bounds__(256, 2)
void k_fc2(const float* __restrict__ sc, const float* __restrict__ w2, float* __restrict__ out2) {
    __shared__ float Ast[32 * 132];
    __shared__ float Bst[32 * 132];
    const int bm = blockIdx.x & 15, bn = blockIdx.x >> 4;
    const int r0 = bm * 128, c0 = bn * 128;
    const int tid = threadIdx.x, ty = tid >> 4, tx = tid & 15;
    const int r = tid >> 1, half = (tid & 1) * 16;

    float acc[8][8];
#pragma unroll
    for (int i = 0; i < 8; ++i)
#pragma unroll
        for (int j = 0; j < 8; ++j) acc[i][j] = 0.0f;

    for (int t0 = 0; t0 < 192; t0 += 32) {
        float4 av[4], bv[4];
        const float4* ga = (const float4*)(sc + (size_t)(r0 + r) * 192 + t0 + half);
        const float4* gb = (const float4*)(w2 + (size_t)(c0 + r) * 192 + t0 + half);
#pragma unroll
        for (int e = 0; e < 4; ++e) { av[e] = ga[e]; bv[e] = gb[e]; }
        __syncthreads();
#pragma unroll
        for (int e = 0; e < 4; ++e) {
            int t = half + 4 * e;
            Ast[(t + 0) * 132 + r] = av[e].x;  Bst[(t + 0) * 132 + r] = bv[e].x;
            Ast[(t + 1) * 132 + r] = av[e].y;  Bst[(t + 1) * 132 + r] = bv[e].y;
            Ast[(t + 2) * 132 + r] = av[e].z;  Bst[(t + 2) * 132 + r] = bv[e].z;
            Ast[(t + 3) * 132 + r] = av[e].w;  Bst[(t + 3) * 132 + r] = bv[e].w;
        }
        __syncthreads();
#pragma unroll 4
        for (int kk = 0; kk < 32; ++kk) {
            const float4* ap = (const float4*)(Ast + kk * 132 + ty * 8);
            const float4* bp = (const float4*)(Bst + kk * 132 + tx * 8);
            float4 A0 = ap[0], A1 = ap[1];
            float4 B0 = bp[0], B1 = bp[1];
            float a[8] = {A0.x, A0.y, A0.z, A0.w, A1.x, A1.y, A1.z, A1.w};
            float b[8] = {B0.x, B0.y, B0.z, B0.w, B1.x, B1.y, B1.z, B1.w};
#pragma unroll
            for (int i = 0; i < 8; ++i)
#pragma unroll
                for (int j = 0; j < 8; ++j)
                    acc[i][j] = fmaf(a[i], b[j], acc[i][j]);
        }
    }
#pragma unroll
    for (int i = 0; i < 8; ++i) {
        float4* op = (float4*)(out2 + (size_t)(r0 + ty * 8 + i) * 2048 + c0 + tx * 8);
        op[0] = make_float4(acc[i][0], acc[i][1], acc[i][2], acc[i][3]);
        op[1] = make_float4(acc[i][4], acc[i][5], acc[i][6], acc[i][7]);
    }
}

__global__ void k_colp(const float* __restrict__ out2, float* __restrict__ colp) {
    const int bc = blockIdx.x & 7, br = blockIdx.x >> 3;
    const int j = bc * 256 + threadIdx.x;
    float s = 0.0f, s2 = 0.0f;
    for (int rr = br * 64; rr < br * 64 + 64; ++rr) {
        float vv = out2[(size_t)rr * 2048 + j];
        s += vv; s2 += vv * vv;
    }
    colp[((size_t)br * 2048 + j) * 2 + 0] = s;
    colp[((size_t)br * 2048 + j) * 2 + 1] = s2;
}

__global__ void k_colf(const float* __restrict__ colp, float* __restrict__ m2r2) {
    const int j = blockIdx.x * 256 + threadIdx.x;
    if (j >= 2048) return;
    float s = 0.0f, s2 = 0.0f;
    for (int br = 0; br < 32; ++br) {
        s  += colp[((size_t)br * 2048 + j) * 2 + 0];
        s2 += colp[((size_t)br * 2048 + j) * 2 + 1];
    }
    float m = s * (1.0f / 2048.0f);
    float var = s2 * (1.0f / 2048.0f) - m * m;
    m2r2[j * 2 + 0] = m;
    m2r2[j * 2 + 1] = rsqrtf(var + EPS);
}

__global__ void k_fc3(const float* __restrict__ out2, const float* __restrict__ m2r2,
                      const float* __restrict__ w3, float* __restrict__ y) {
    const int rr = blockIdx.x;
    const int tid = threadIdx.x;
    __shared__ float red[4];
    float s = 0.0f;
    for (int j = tid; j < 2048; j += 256) {
        float2 mr = ((const float2*)m2r2)[j];
        float vv = (out2[(size_t)rr * 2048 + j] - mr.x) * mr.y;
        vv = fmaxf(vv, 0.0f);
        s += vv * w3[j];
    }
#pragma unroll
    for (int off = 32; off; off >>= 1) s += __shfl_xor(s, off);
    if ((tid & 63) == 0) red[tid >> 6] = s;
    __syncthreads();
    if (tid == 0) y[rr] = red[0] + red[1] + red[2] + red[3];
}

__global__ void k_bn3(const float* __restrict__ y, float* __restrict__ score, int first) {
    const int tid = threadIdx.x;
    __shared__ float rs[4], rs2[4];
    float p[4]; float s = 0.0f, s2 = 0.0f;
#pragma unroll
    for (int u = 0; u < 4; ++u) {
        int i = tid + (u << 8);
        float vv = y[2 * i] + y[2 * i + 1];
        p[u] = vv; s += vv; s2 += vv * vv;
    }
#pragma unroll
    for (int off = 32; off; off >>= 1) { s += __shfl_xor(s, off); s2 += __shfl_xor(s2, off); }
    if ((tid & 63) == 0) { rs[tid >> 6] = s; rs2[tid >> 6] = s2; }
    __syncthreads();
    float S = rs[0] + rs[1] + rs[2] + rs[3];
    float S2 = rs2[0] + rs2[1] + rs2[2] + rs2[3];
    float m = S * (1.0f / 1024.0f);
    float var = S2 * (1.0f / 1024.0f) - m * m;
    float rstd = rsqrtf(var + EPS);
#pragma unroll
    for (int u = 0; u < 4; ++u) {
        int i = tid + (u << 8);
        float vv = (p[u] - m) * rstd;
        score[i] = first ? vv : (score[i] + vv);
    }
}

__global__ void k_final(const float* __restrict__ score, float* __restrict__ out) {
    const int tid = threadIdx.x;
    __shared__ float rs[4], rs2[4];
    float p[4]; float s = 0.0f, s2 = 0.0f;
#pragma unroll
    for (int u = 0; u < 4; ++u) {
        int i = tid + (u << 8);
        float vv = score[i];
        p[u] = vv; s += vv; s2 += vv * vv;
    }
#pragma unroll
    for (int off = 32; off; off >>= 1) { s += __shfl_xor(s, off); s2 += __shfl_xor(s2, off); }
    if ((tid & 63) == 0) { rs[tid >> 6] = s; rs2[tid >> 6] = s2; }
    __syncthreads();
    float S = rs[0] + rs[1] + rs[2] + rs[3];
    float S2 = rs2[0] + rs2[1] + rs2[2] + rs2[3];
    float m = S * (1.0f / 1024.0f);
    float var = S2 * (1.0f / 1024.0f) - m * m;
    float rstd = rsqrtf(var + EPS);
#pragma unroll
    for (int u = 0; u < 4; ++u) {
        int i = tid + (u << 8);
        out[i] = (p[u] - m) * rstd;
    }
}

// ---------------- launch ----------------
extern "C" void kernel_launch(void* const* d_in, const int* in_sizes, int n_in,
                              void* d_out, int out_size, void* d_ws, size_t ws_size,
                              hipStream_t stream) {
    const float* gallery = (const float*)d_in[0];
    const float* query   = (const float*)d_in[1];
    float* ws = (float*)d_ws;

    const bool batched = (ws_size >= (size_t)B_TOTAL * sizeof(float));

    if (batched) {
        short* scp = (short*)(ws + B_SCPF);
        short* w2p = (short*)(ws + B_W2PF);

        k_sigse<<<(3 * 36864 + 255) / 256, 256, 0, stream>>>(
            (const float*)d_in[2 + 0 * 7 + 2], (const float*)d_in[2 + 1 * 7 + 2],
            (const float*)d_in[2 + 2 * 7 + 2], ws + B_SIGSE);
        k_w1t_b<<<(3 * CPAD * MPAD + 255) / 256, 256, 0, stream>>>(
            (const float*)d_in[2 + 0 * 7 + 0], (const float*)d_in[2 + 1 * 7 + 0],
            (const float*)d_in[2 + 2 * 7 + 0], ws + B_W1T);
        k_fc1_b<<<dim3(3, 32, 6), 256, 0, stream>>>(
            gallery, query, ws + B_W1T,
            (const float*)d_in[2 + 0 * 7 + 1], (const float*)d_in[2 + 1 * 7 + 1],
            (const float*)d_in[2 + 2 * 7 + 1], ws + B_SLAB);
        k_pack_b<<<dim3(KSTEPS, 32, 6), 384, 0, stream>>>(ws + B_SLAB, (short*)(ws + B_PACKF));
        k_w2p<<<dim3(64, 3), 256, 0, stream>>>(
            (const float*)d_in[2 + 0 * 7 + 3], (const float*)d_in[2 + 1 * 7 + 3],
            (const float*)d_in[2 + 2 * 7 + 3], w2p);
        k_corr_b<<<dim3(1024, 3), 256, 0, stream>>>((const short*)(ws + B_PACKF),
                                                    ws + B_SIGSE, scp);
        k_fc2m_b<<<dim3(256, 3), 256, 0, stream>>>(scp, w2p, ws + B_OUT2, ws + B_COLP);
        k_colf_b<<<24, 256, 0, stream>>>(ws + B_COLP, ws + B_M2R2);
        k_fc3_b<<<dim3(2048, 3), 256, 0, stream>>>(
            ws + B_OUT2, ws + B_M2R2,
            (const float*)d_in[2 + 0 * 7 + 5], (const float*)d_in[2 + 1 * 7 + 5],
            (const float*)d_in[2 + 2 * 7 + 5], ws + B_Y);
        k_bn3_b<<<3, 256, 0, stream>>>(ws + B_Y, ws + B_SC3);
        k_final3<<<1, 256, 0, stream>>>(ws + B_SC3, (float*)d_out);
        return;
    }

    // ---- fallback: proven per-layer pipeline (28.1 MB ws) ----
    const int cs[3] = {171, 171, 170};
    const int st[3] = {0, 171, 342};

    short* qpack = (short*)(ws + OFF_QPACK);
    short* kpack = (short*)(ws + OFF_KPACK);

    k_sigse<<<(3 * 36864 + 255) / 256, 256, 0, stream>>>(
        (const float*)d_in[2 + 0 * 7 + 2], (const float*)d_in[2 + 1 * 7 + 2],
        (const float*)d_in[2 + 2 * 7 + 2], ws + OFF_SIGSE);

    for (int l = 0; l < 3; ++l) {
        const float* w1 = (const float*)d_in[2 + l * 7 + 0];
        const float* b1 = (const float*)d_in[2 + l * 7 + 1];
        const float* w2 = (const float*)d_in[2 + l * 7 + 3];
        const float* w3 = (const float*)d_in[2 + l * 7 + 5];

        k_w1t<<<(CPAD * CPAD + 255) / 256, 256, 0, stream>>>(w1, cs[l], ws + OFF_W1T);
        k_fc1<<<dim3(3, 32, 2), 256, 0, stream>>>(gallery, query, ws + OFF_W1T, b1,
                                                  cs[l], st[l], ws + OFF_QSLAB, ws + OFF_KSLAB);
        k_pack<<<dim3(KSTEPS, 32, 2), 384, 0, stream>>>(ws + OFF_QSLAB, ws + OFF_KSLAB,
                                                        qpack, kpack);
        k_corr<<<1024, 256, 0, stream>>>(qpack, kpack, ws + OFF_SIGSE + l * 36864, ws + OFF_SC);
        k_fc2<<<256, 256, 0, stream>>>(ws + OFF_SC, w2, ws + OFF_OUT2);
        k_colp<<<256, 256, 0, stream>>>(ws + OFF_OUT2, ws + OFF_COLP);
        k_colf<<<8, 256, 0, stream>>>(ws + OFF_COLP, ws + OFF_M2V2);
        k_fc3<<<2048, 256, 0, stream>>>(ws + OFF_OUT2, ws + OFF_M2V2, w3, ws + OFF_Y);
        k_bn3<<<1, 256, 0, stream>>>(ws + OFF_Y, ws + OFF_SCORE, l == 0 ? 1 : 0);
    }
    k_final<<<1, 256, 0, stream>>>(ws + OFF_SCORE, (float*)d_out);
}

// Round 8
// 337.264 us; speedup vs baseline: 3.4197x; 1.1064x over previous
//
#include <hip/hip_runtime.h>
#include <math.h>

// ---------------- constants ----------------
#define EPS 1e-5f
#define TOTAL_IN (32*512*192)   // floats per input tensor (gallery/query)
#define CPAD 176                // K-pad: 171 -> 11*16 (11 MFMA k-steps)
#define MPAD 192                // fc1 M-pad: 176 -> 192 = 16*12 (vector A-reads)
#define KSTEPS 11
#define PACK_BK 6144            // shorts per (b,kstep): 2 planes * 6 tiles * 64 lanes * 8

// ======== fallback (per-layer) workspace offsets, floats (28.1 MB) ========
#define OFF_SIGSE 0u
#define OFF_W1T   110592u
#define OFF_QPACK 141568u
#define OFF_KPACK 1222912u
#define OFF_SC    2304256u
#define OFF_OUT2  2697472u
#define OFF_QSLAB OFF_OUT2
#define OFF_KSLAB (OFF_OUT2 + 1081344u)
#define OFF_COLP  6891776u
#define OFF_M2V2  7022848u
#define OFF_Y     7026944u
#define OFF_SCORE 7028992u

// ======== batched (3-layer) workspace offsets, floats (63.1 MB) ========
#define B_SIGSE 0u              // 110592
#define B_W1T   110592u         // 3*176*192 = 101376
#define B_SCPF  211968u         // sc packs: 3*786432 shorts = 1179648 floats
#define B_W2PF  1391616u        // w2 packs: 1179648 floats
#define B_COLP  2571264u        // 3*16*2048*2 = 196608
#define B_M2R2  2767872u        // 12288
#define B_Y     2780160u        // 6144
#define B_SC3   2786304u        // 3072
#define B_BIG   2789376u        // packs live at B_PACKF; out2 overlays B_BIG after corr consumed packs
#define B_PACKF (B_BIG + 6488064u)
#define B_OUT2  B_BIG
#define B_TOTAL 15765504u       // floats = 63,062,016 bytes

typedef __attribute__((ext_vector_type(8)))  short short8;
typedef __attribute__((ext_vector_type(16))) float f32x16;

__device__ __forceinline__ unsigned short f2bf(float x) {
    unsigned u = __float_as_uint(x);
    u += 0x7fffu + ((u >> 16) & 1u);
    return (unsigned short)(u >> 16);
}
__device__ __forceinline__ float bf2f(unsigned short h) {
    return __uint_as_float(((unsigned)h) << 16);
}

__device__ __forceinline__ void g2lds16(const void* g, void* l) {
    __builtin_amdgcn_global_load_lds((const __attribute__((address_space(1))) unsigned int*)g,
                                     (__attribute__((address_space(3))) unsigned int*)l, 16, 0, 0);
}

// ---------------- shared tiny kernel ----------------
__global__ void k_sigse(const float* __restrict__ se0, const float* __restrict__ se1,
                        const float* __restrict__ se2, float* __restrict__ dst) {
    int idx = blockIdx.x * 256 + threadIdx.x;
    if (idx >= 3 * 36864) return;
    int l = idx / 36864, r = idx % 36864;
    const float* se = (l == 0) ? se0 : ((l == 1) ? se1 : se2);
    float x = se[r];
    dst[idx] = 1.0f / (1.0f + __expf(-x));
}

// ================================================================
//                      BATCHED (3-layer) PATH
// ================================================================

// w1t[l][i][j] (M-padded): [176 k][192 j]
__global__ void k_w1t_b(const float* __restrict__ w1_0, const float* __restrict__ w1_1,
                        const float* __restrict__ w1_2, float* __restrict__ w1t) {
    int idx = blockIdx.x * 256 + threadIdx.x;
    if (idx >= 3 * CPAD * MPAD) return;
    int l = idx / (CPAD * MPAD), r = idx % (CPAD * MPAD);
    int i = r / MPAD, j = r % MPAD;
    int c = (l == 2) ? 170 : 171;
    const float* w1 = (l == 0) ? w1_0 : ((l == 1) ? w1_1 : w1_2);
    w1t[idx] = (i < c && j < c) ? w1[j * c + i] : 0.0f;
}

// fc1 + fused hi/lo pack: grid (3 quad, 32 b, 6=l*2+tensor)
// writes packs[z][b][kstep][plane][tile][lane][8] directly (no fp32 slab)
__global__ __launch_bounds__(256, 4)
void k_fc1p_b(const float* __restrict__ g0, const float* __restrict__ g1,
              const float* __restrict__ w1tb,
              const float* __restrict__ b1_0, const float* __restrict__ b1_1,
              const float* __restrict__ b1_2, short* __restrict__ packs) {
    __shared__ float smem[8192];          // 32 KB; As=6144, Bs=2048; epilogue reuses [0..6336)
    float* As = smem;
    float* Bs = smem + 6144;
    const int quad = blockIdx.x, b = blockIdx.y, z = blockIdx.z;
    const int l = z >> 1;
    const int c = (l == 2) ? 170 : 171, st = l * 171;
    const float* inp = (z & 1) ? g1 : g0;
    const float* w1t = w1tb + (unsigned)l * (CPAD * MPAD);
    const float* b1 = (l == 0) ? b1_0 : ((l == 1) ? b1_1 : b1_2);
    short* dstb = packs + (size_t)z * 2162688u + (size_t)b * (KSTEPS * PACK_BK);
    const int tid = threadIdx.x, ty = tid >> 4, tx = tid & 15;
    const int lane = tid & 63, w = tid >> 6;
    const size_t boff = (size_t)b * 98304 + (size_t)st * 192 + (size_t)quad * 64;

    float acc[12][4];
#pragma unroll
    for (int i = 0; i < 12; ++i)
#pragma unroll
        for (int j = 0; j < 4; ++j) acc[i][j] = 0.0f;

    // staging: A 768 float4, B 256 float4 => 1024 = 4/thread
    float4 v[4];
    auto load_chunk = [&](int ci) {
#pragma unroll
        for (int e = 0; e < 4; ++e) {
            int f = tid + (e << 8);
            if (f < 768) {
                v[e] = *(const float4*)(w1t + ci * 3072 + f * 4);
            } else {
                int f2 = f - 768;
                int r = f2 >> 4, c4 = f2 & 15;
                size_t off = boff + (size_t)(ci * 16 + r) * 192 + c4 * 4;
                if (off > (size_t)(TOTAL_IN - 4)) off = (size_t)(TOTAL_IN - 4); // layer-2 tail clamp (A rows are 0 there)
                v[e] = *(const float4*)(inp + off);
            }
        }
    };
    auto write_chunk = [&](int buf) {
        float* Ad = As + buf * 3072;
        float* Bd = Bs + buf * 1024;
#pragma unroll
        for (int e = 0; e < 4; ++e) {
            int f = tid + (e << 8);
            if (f < 768) *(float4*)(Ad + f * 4) = v[e];
            else         *(float4*)(Bd + (f - 768) * 4) = v[e];
        }
    };

    load_chunk(0); write_chunk(0);
    __syncthreads();

    for (int ci = 0; ci < 11; ++ci) {
        const int buf = ci & 1;
        const bool pf = (ci + 1 < 11);
        if (pf) load_chunk(ci + 1);

        const float* Aw = As + buf * 3072 + ty * 12;
        const float* Bw = Bs + buf * 1024 + tx * 4;
#pragma unroll 2
        for (int kk = 0; kk < 16; ++kk) {
            const float4* ap = (const float4*)(Aw + kk * MPAD);
            float4 A0 = ap[0], A1 = ap[1], A2 = ap[2];
            float a[12] = {A0.x, A0.y, A0.z, A0.w, A1.x, A1.y, A1.z, A1.w, A2.x, A2.y, A2.z, A2.w};
            float4 B0 = *(const float4*)(Bw + kk * 64);
            float bb[4] = {B0.x, B0.y, B0.z, B0.w};
#pragma unroll
            for (int i = 0; i < 12; ++i)
#pragma unroll
                for (int j = 0; j < 4; ++j)
                    acc[i][j] = fmaf(a[i], bb[j], acc[i][j]);
        }
        if (pf) write_chunk(buf ^ 1);
        __syncthreads();
    }

    // fused pack epilogue: two 32-col halves through LDS [192][33]
    const int hf = lane >> 5, col = lane & 31;
#pragma unroll
    for (int h = 0; h < 2; ++h) {
        __syncthreads();                        // LDS free (main loop / prev half done)
        if ((tx >> 3) == h) {
            const int tc = (tx & 7) * 4;
#pragma unroll
            for (int i = 0; i < 12; ++i) {
                int j = ty * 12 + i;
                bool valid = (j < c);
                float bias = valid ? b1[j] : 0.0f;
#pragma unroll
                for (int jj = 0; jj < 4; ++jj)
                    smem[j * 33 + tc + jj] = valid ? (acc[i][jj] + bias) : 0.0f;
            }
        }
        __syncthreads();
        const int tile = quad * 2 + h;
        for (int ks = w; ks < KSTEPS; ks += 4) {
            short8 H, L;
#pragma unroll
            for (int e = 0; e < 8; ++e) {
                float vv = smem[(ks * 16 + hf * 8 + e) * 33 + col];
                unsigned short hh = f2bf(vv);
                H[e] = (short)hh;
                L[e] = (short)f2bf(vv - bf2f(hh));
            }
            short8* dst = (short8*)(dstb + (size_t)ks * PACK_BK);
            dst[(0 * 6 + tile) * 64 + lane] = H;
            dst[(1 * 6 + tile) * 64 + lane] = L;
        }
    }
}

// w2 -> B-fragment hi/lo pack: grid (64 jtiles, 3 l), 256 thr
__global__ void k_w2p(const float* __restrict__ w2_0, const float* __restrict__ w2_1,
                      const float* __restrict__ w2_2, short* __restrict__ w2p) {
    const int jt = blockIdx.x, l = blockIdx.y;
    const float* w2 = (l == 0) ? w2_0 : ((l == 1) ? w2_1 : w2_2);
    short* WP = w2p + (size_t)l * 786432u;
    const int tid = threadIdx.x, lane = tid & 63, sub = tid >> 6;
    const int j = jt * 32 + (lane & 31), hf = lane >> 5;
#pragma unroll
    for (int kk = 0; kk < 3; ++kk) {
        int ks = sub * 3 + kk;
        const float4* src = (const float4*)(w2 + (size_t)j * 192 + ks * 16 + hf * 8);
        float4 a = src[0], b = src[1];
        float v[8] = {a.x, a.y, a.z, a.w, b.x, b.y, b.z, b.w};
        short8 H, L;
#pragma unroll
        for (int e = 0; e < 8; ++e) {
            unsigned short h = f2bf(v[e]);
            H[e] = (short)h;
            L[e] = (short)f2bf(v[e] - bf2f(h));
        }
        ((short8*)WP)[((jt * 12 + ks) * 2 + 0) * 64 + lane] = H;
        ((short8*)WP)[((jt * 12 + ks) * 2 + 1) * 64 + lane] = L;
    }
}

// corr batched: grid 3072 (XCD-swizzled); epilogue emits sc as fc2 A-fragments
__global__ __launch_bounds__(256, 2)
void k_corr_b(const short* __restrict__ packs, const float* __restrict__ sigb,
              short* __restrict__ scp) {
    __shared__ short smem[2 * 12288];
    // XCD swizzle: 3072 = 8 XCDs * 384; give each XCD 12 contiguous q-rows of one layer
    const int orig = blockIdx.x;
    const int swz = (orig & 7) * 384 + (orig >> 3);
    const int l = swz >> 10, qk = swz & 1023;
    const int q = qk >> 5, k = qk & 31;
    const int tid = threadIdx.x, lane = tid & 63, w = tid >> 6;
    const int ws = w >> 1, wt = w & 1;
    const short* qpack = packs + (size_t)(l * 2 + 0) * 2162688u;
    const short* kpack = packs + (size_t)(l * 2 + 1) * 2162688u;
    const float* sig = sigb + (unsigned)l * 36864u;
    short* scpl = scp + (size_t)l * 786432u;
    const char* Abase = (const char*)(kpack + (size_t)k * KSTEPS * PACK_BK);
    const char* Bbase = (const char*)(qpack + (size_t)q * KSTEPS * PACK_BK);

    f32x16 acc[3][3];
#pragma unroll
    for (int i = 0; i < 3; ++i)
#pragma unroll
        for (int j = 0; j < 3; ++j)
#pragma unroll
            for (int r = 0; r < 16; ++r) acc[i][j][r] = 0.0f;

    auto stage = [&](int buf, int ks) {
#pragma unroll
        for (int u = 0; u < 6; ++u) {
            int c = u * 4 + w;
            const char* g = (c < 12 ? Abase + (size_t)ks * 12288 + c * 1024
                                    : Bbase + (size_t)ks * 12288 + (c - 12) * 1024) + lane * 16;
            g2lds16(g, (char*)smem + buf * 24576 + c * 1024);
        }
    };

    stage(0, 0);
    __syncthreads();

    int buf = 0;
    for (int ks = 0; ks < KSTEPS; ++ks) {
        if (ks + 1 < KSTEPS) stage(buf ^ 1, ks + 1);

        const short8* LA = (const short8*)((const char*)smem + buf * 24576);
        const short8* LB = (const short8*)((const char*)smem + buf * 24576 + 12288);
        short8 Ah[3], Al[3], Bh[3], Bl[3];
#pragma unroll
        for (int u = 0; u < 3; ++u) {
            Ah[u] = LA[(0 * 6 + ws * 3 + u) * 64 + lane];
            Al[u] = LA[(1 * 6 + ws * 3 + u) * 64 + lane];
            Bh[u] = LB[(0 * 6 + wt * 3 + u) * 64 + lane];
            Bl[u] = LB[(1 * 6 + wt * 3 + u) * 64 + lane];
        }
#pragma unroll
        for (int i = 0; i < 3; ++i)
#pragma unroll
            for (int j = 0; j < 3; ++j) {
                acc[i][j] = __builtin_amdgcn_mfma_f32_32x32x16_bf16(Ah[i], Bh[j], acc[i][j], 0, 0, 0);
                acc[i][j] = __builtin_amdgcn_mfma_f32_32x32x16_bf16(Al[i], Bh[j], acc[i][j], 0, 0, 0);
                acc[i][j] = __builtin_amdgcn_mfma_f32_32x32x16_bf16(Ah[i], Bl[j], acc[i][j], 0, 0, 0);
            }
        __syncthreads();
        buf ^= 1;
    }

    const int col = lane & 31, hf = lane >> 5;
    float* scr = (float*)smem;
    float cm[3] = {-3.0e38f, -3.0e38f, -3.0e38f};
#pragma unroll
    for (int i = 0; i < 3; ++i) {
        const int sbase = (ws * 3 + i) * 32;
        float rv[16];
#pragma unroll
        for (int r = 0; r < 16; ++r) rv[r] = -3.0e38f;
#pragma unroll
        for (int j = 0; j < 3; ++j) {
            const int tb = (wt * 3 + j) * 32 + col;
#pragma unroll
            for (int r = 0; r < 16; ++r) {
                int row = (r & 3) + 8 * (r >> 2) + 4 * hf;
                float v = acc[i][j][r] * sig[(size_t)(sbase + row) * 192 + tb];
                rv[r] = fmaxf(rv[r], v);
                cm[j] = fmaxf(cm[j], v);
            }
        }
#pragma unroll
        for (int m = 1; m < 32; m <<= 1)
#pragma unroll
            for (int r = 0; r < 16; ++r) rv[r] = fmaxf(rv[r], __shfl_xor(rv[r], m));
#pragma unroll
        for (int r = 0; r < 16; ++r)
            if (col == r)
                scr[384 + wt * 192 + sbase + (r & 3) + 8 * (r >> 2) + 4 * hf] = rv[r];
    }
#pragma unroll
    for (int j = 0; j < 3; ++j) {
        float c2 = fmaxf(cm[j], __shfl_xor(cm[j], 32));
        if (hf == 0) scr[ws * 192 + (wt * 3 + j) * 32 + col] = c2;
    }
    __syncthreads();
    // pack rows 2qk (per-t max) and 2qk+1 (per-s max) as fc2 A-fragments
    if (tid < 96) {
        const int row = tid / 48, rem = tid % 48;
        const int ks2 = rem >> 2, hf2 = (rem >> 1) & 1, pl = rem & 1;
        const int r = 2 * qk + row;
        const float* s0 = scr + row * 384;
        short8 o;
#pragma unroll
        for (int e = 0; e < 8; ++e) {
            int t = ks2 * 16 + hf2 * 8 + e;
            float v = fmaxf(s0[t], s0[192 + t]);
            unsigned short h = f2bf(v);
            o[e] = pl ? (short)f2bf(v - bf2f(h)) : (short)h;
        }
        ((short8*)scpl)[(((r >> 5) * 12 + ks2) * 2 + pl) * 64 + (hf2 * 32 + (r & 31))] = o;
    }
}

// fc2 MFMA (split-bf16) + fused BN2 column partials: grid (256, 3)
__global__ __launch_bounds__(256, 2)
void k_fc2m_b(const short* __restrict__ scp, const short* __restrict__ w2p,
              float* __restrict__ out2b, float* __restrict__ colpb) {
    __shared__ short smem[2 * 8192];   // per buf 16KB: A 8x1KB | B 8x1KB
    const int rblk = blockIdx.x & 15, nblk = blockIdx.x >> 4, l = blockIdx.y;
    float* out2 = out2b + (size_t)l * 4194304u;
    float* colp = colpb + (size_t)l * 65536u;
    const int tid = threadIdx.x, lane = tid & 63, w = tid >> 6;
    const int wr = w >> 1, wc = w & 1;
    const char* SPb = (const char*)(scp + (size_t)l * 786432u + (size_t)rblk * 4 * 12288u);
    const char* WPb = (const char*)(w2p + (size_t)l * 786432u + (size_t)nblk * 4 * 12288u);

    f32x16 acc[2][2];
#pragma unroll
    for (int i = 0; i < 2; ++i)
#pragma unroll
        for (int j = 0; j < 2; ++j)
#pragma unroll
            for (int r = 0; r < 16; ++r) acc[i][j][r] = 0.0f;

    auto stage = [&](int buf, int ks) {
#pragma unroll
        for (int u = 0; u < 4; ++u) {
            int c = u * 4 + w;
            const char* g = (c < 8 ? SPb + (c >> 1) * 24576 + ks * 2048 + (c & 1) * 1024
                                   : WPb + ((c - 8) >> 1) * 24576 + ks * 2048 + (c & 1) * 1024) + lane * 16;
            g2lds16(g, (char*)smem + buf * 16384 + c * 1024);
        }
    };

    stage(0, 0);
    __syncthreads();

    int buf = 0;
    for (int ks = 0; ks < 12; ++ks) {
        if (ks + 1 < 12) stage(buf ^ 1, ks + 1);

        const char* base = (const char*)smem + buf * 16384;
        short8 Ah[2], Al[2], Bh[2], Bl[2];
#pragma unroll
        for (int mt = 0; mt < 2; ++mt) {
            Ah[mt] = *(const short8*)(base + ((wr * 2 + mt) * 2 + 0) * 1024 + lane * 16);
            Al[mt] = *(const short8*)(base + ((wr * 2 + mt) * 2 + 1) * 1024 + lane * 16);
        }
#pragma unroll
        for (int nt = 0; nt < 2; ++nt) {
            Bh[nt] = *(const short8*)(base + 8192 + ((wc * 2 + nt) * 2 + 0) * 1024 + lane * 16);
            Bl[nt] = *(const short8*)(base + 8192 + ((wc * 2 + nt) * 2 + 1) * 1024 + lane * 16);
        }
#pragma unroll
        for (int mt = 0; mt < 2; ++mt)
#pragma unroll
            for (int nt = 0; nt < 2; ++nt) {
                acc[mt][nt] = __builtin_amdgcn_mfma_f32_32x32x16_bf16(Ah[mt], Bh[nt], acc[mt][nt], 0, 0, 0);
                acc[mt][nt] = __builtin_amdgcn_mfma_f32_32x32x16_bf16(Al[mt], Bh[nt], acc[mt][nt], 0, 0, 0);
                acc[mt][nt] = __builtin_amdgcn_mfma_f32_32x32x16_bf16(Ah[mt], Bl[nt], acc[mt][nt], 0, 0, 0);
            }
        __syncthreads();
        buf ^= 1;
    }

    const int hf = lane >> 5, cl = lane & 31;
#pragma unroll
    for (int mt = 0; mt < 2; ++mt)
#pragma unroll
        for (int nt = 0; nt < 2; ++nt) {
            const int c0 = nblk * 128 + (wc * 2 + nt) * 32 + cl;
#pragma unroll
            for (int r = 0; r < 16; ++r) {
                int row = rblk * 128 + (wr * 2 + mt) * 32 + (r & 3) + 8 * (r >> 2) + 4 * hf;
                out2[(size_t)row * 2048 + c0] = acc[mt][nt][r];
            }
        }
    float* cs = (float*)smem;
    float* cq = cs + 512;
#pragma unroll
    for (int nt = 0; nt < 2; ++nt) {
        float s = 0.0f, q2 = 0.0f;
#pragma unroll
        for (int mt = 0; mt < 2; ++mt)
#pragma unroll
            for (int r = 0; r < 16; ++r) { float v = acc[mt][nt][r]; s += v; q2 += v * v; }
        int ci = (wc * 2 + nt) * 32 + cl;
        cs[ci * 4 + wr * 2 + hf] = s;
        cq[ci * 4 + wr * 2 + hf] = q2;
    }
    __syncthreads();
    if (tid < 128) {
        float s = 0.0f, q2 = 0.0f;
#pragma unroll
        for (int u = 0; u < 4; ++u) { s += cs[tid * 4 + u]; q2 += cq[tid * 4 + u]; }
        colp[((size_t)rblk * 2048 + nblk * 128 + tid) * 2 + 0] = s;
        colp[((size_t)rblk * 2048 + nblk * 128 + tid) * 2 + 1] = q2;
    }
}

// reduce 16 row-block partials -> mean/rstd per (l, j). grid 24
__global__ void k_colf_b(const float* __restrict__ colpb, float* __restrict__ m2r2b) {
    const int idx = blockIdx.x * 256 + threadIdx.x;
    if (idx >= 3 * 2048) return;
    const int l = idx >> 11, j = idx & 2047;
    const float* colp = colpb + (size_t)l * 65536u;
    float s = 0.0f, s2 = 0.0f;
    for (int bm = 0; bm < 16; ++bm) {
        s  += colp[((size_t)bm * 2048 + j) * 2 + 0];
        s2 += colp[((size_t)bm * 2048 + j) * 2 + 1];
    }
    float m = s * (1.0f / 2048.0f);
    float var = s2 * (1.0f / 2048.0f) - m * m;
    m2r2b[(size_t)l * 4096 + j * 2 + 0] = m;
    m2r2b[(size_t)l * 4096 + j * 2 + 1] = rsqrtf(var + EPS);
}

// fused BN2+relu+fc3: grid (2048, 3)
__global__ void k_fc3_b(const float* __restrict__ out2b, const float* __restrict__ m2r2b,
                        const float* __restrict__ w3_0, const float* __restrict__ w3_1,
                        const float* __restrict__ w3_2, float* __restrict__ yb) {
    const int rr = blockIdx.x, l = blockIdx.y;
    const float* out2 = out2b + (size_t)l * 4194304u;
    const float* m2r2 = m2r2b + (size_t)l * 4096u;
    const float* w3 = (l == 0) ? w3_0 : ((l == 1) ? w3_1 : w3_2);
    const int tid = threadIdx.x;
    __shared__ float red[4];
    float s = 0.0f;
    for (int j = tid; j < 2048; j += 256) {
        float2 mr = ((const float2*)m2r2)[j];
        float vv = (out2[(size_t)rr * 2048 + j] - mr.x) * mr.y;
        vv = fmaxf(vv, 0.0f);
        s += vv * w3[j];
    }
#pragma unroll
    for (int off = 32; off; off >>= 1) s += __shfl_xor(s, off);
    if ((tid & 63) == 0) red[tid >> 6] = s;
    __syncthreads();
    if (tid == 0) yb[(size_t)l * 2048 + rr] = red[0] + red[1] + red[2] + red[3];
}

// pair-sum + BN3 per layer: grid 3
__global__ void k_bn3_b(const float* __restrict__ yb, float* __restrict__ sc3) {
    const int l = blockIdx.x, tid = threadIdx.x;
    const float* y = yb + (size_t)l * 2048u;
    __shared__ float rs[4], rs2[4];
    float p[4]; float s = 0.0f, s2 = 0.0f;
#pragma unroll
    for (int u = 0; u < 4; ++u) {
        int i = tid + (u << 8);
        float vv = y[2 * i] + y[2 * i + 1];
        p[u] = vv; s += vv; s2 += vv * vv;
    }
#pragma unroll
    for (int off = 32; off; off >>= 1) { s += __shfl_xor(s, off); s2 += __shfl_xor(s2, off); }
    if ((tid & 63) == 0) { rs[tid >> 6] = s; rs2[tid >> 6] = s2; }
    __syncthreads();
    float S = rs[0] + rs[1] + rs[2] + rs[3];
    float S2 = rs2[0] + rs2[1] + rs2[2] + rs2[3];
    float m = S * (1.0f / 1024.0f);
    float var = S2 * (1.0f / 1024.0f) - m * m;
    float rstd = rsqrtf(var + EPS);
#pragma unroll
    for (int u = 0; u < 4; ++u) {
        int i = tid + (u << 8);
        sc3[(size_t)l * 1024 + i] = (p[u] - m) * rstd;
    }
}

// sum 3 layers + final BN
__global__ void k_final3(const float* __restrict__ sc3, float* __restrict__ out) {
    const int tid = threadIdx.x;
    __shared__ float rs[4], rs2[4];
    float p[4]; float s = 0.0f, s2 = 0.0f;
#pragma unroll
    for (int u = 0; u < 4; ++u) {
        int i = tid + (u << 8);
        float vv = sc3[i] + sc3[1024 + i] + sc3[2048 + i];
        p[u] = vv; s += vv; s2 += vv * vv;
    }
#pragma unroll
    for (int off = 32; off; off >>= 1) { s += __shfl_xor(s, off); s2 += __shfl_xor(s2, off); }
    if ((tid & 63) == 0) { rs[tid >> 6] = s; rs2[tid >> 6] = s2; }
    __syncthreads();
    float S = rs[0] + rs[1] + rs[2] + rs[3];
    float S2 = rs2[0] + rs2[1] + rs2[2] + rs2[3];
    float m = S * (1.0f / 1024.0f);
    float var = S2 * (1.0f / 1024.0f) - m * m;
    float rstd = rsqrtf(var + EPS);
#pragma unroll
    for (int u = 0; u < 4; ++u) {
        int i = tid + (u << 8);
        out[i] = (p[u] - m) * rstd;
    }
}

// ================================================================
//              FALLBACK (per-layer) PATH — proven R5 code
// ================================================================

__global__ void k_w1t(const float* __restrict__ w1, int c, float* __restrict__ w1t) {
    int idx = blockIdx.x * 256 + threadIdx.x;
    if (idx >= CPAD * CPAD) return;
    int i = idx / CPAD, j = idx % CPAD;
    w1t[idx] = (i < c && j < c) ? w1[j * c + i] : 0.0f;
}

__global__ __launch_bounds__(256, 4)
void k_fc1(const float* __restrict__ g0, const float* __restrict__ g1,
           const float* __restrict__ w1t, const float* __restrict__ b1,
           int c, int st, float* __restrict__ d0, float* __restrict__ d1) {
    __shared__ float As[2 * 16 * CPAD];
    __shared__ float Bs[2 * 16 * 64];
    const int quad = blockIdx.x, b = blockIdx.y, tensor = blockIdx.z;
    const float* inp = tensor ? g1 : g0;
    float* dst = tensor ? d1 : d0;
    const int tid = threadIdx.x, ty = tid >> 4, tx = tid & 15;
    const size_t boff = (size_t)b * 98304 + (size_t)st * 192 + (size_t)quad * 64;

    float acc[11][4];
#pragma unroll
    for (int i = 0; i < 11; ++i)
#pragma unroll
        for (int j = 0; j < 4; ++j) acc[i][j] = 0.0f;

    float4 v[4];
    auto load_chunk = [&](int ci) {
#pragma unroll
        for (int e = 0; e < 4; ++e) {
            int f = tid + (e << 8);
            if (f < 704) {
                v[e] = *(const float4*)(w1t + ci * 2816 + f * 4);
            } else if (f < 960) {
                int f2 = f - 704;
                int r = f2 >> 4, c4 = f2 & 15;
                size_t off = boff + (size_t)(ci * 16 + r) * 192 + c4 * 4;
                if (off > (size_t)(TOTAL_IN - 4)) off = (size_t)(TOTAL_IN - 4);
                v[e] = *(const float4*)(inp + off);
            }
        }
    };
    auto write_chunk = [&](int buf) {
        float* Ad = As + buf * 2816;
        float* Bd = Bs + buf * 1024;
#pragma unroll
        for (int e = 0; e < 4; ++e) {
            int f = tid + (e << 8);
            if (f < 704)      *(float4*)(Ad + f * 4) = v[e];
            else if (f < 960) *(float4*)(Bd + (f - 704) * 4) = v[e];
        }
    };

    load_chunk(0); write_chunk(0);
    __syncthreads();

    for (int ci = 0; ci < 11; ++ci) {
        const int buf = ci & 1;
        const bool pf = (ci + 1 < 11);
        if (pf) load_chunk(ci + 1);

        const float* Aw = As + buf * 2816 + ty * 11;
        const float* Bw = Bs + buf * 1024 + tx * 4;
#pragma unroll 2
        for (int kk = 0; kk < 16; ++kk) {
            float a[11];
#pragma unroll
            for (int i = 0; i < 11; ++i) a[i] = Aw[kk * CPAD + i];
            float4 B0 = *(const float4*)(Bw + kk * 64);
            float bb[4] = {B0.x, B0.y, B0.z, B0.w};
#pragma unroll
            for (int i = 0; i < 11; ++i)
#pragma unroll
                for (int j = 0; j < 4; ++j)
                    acc[i][j] = fmaf(a[i], bb[j], acc[i][j]);
        }
        if (pf) write_chunk(buf ^ 1);
        __syncthreads();
    }

    float* drow = dst + (size_t)b * (CPAD * 192) + quad * 64;
#pragma unroll
    for (int i = 0; i < 11; ++i) {
        int j = ty * 11 + i;
        bool valid = (j < c);
        float bias = valid ? b1[j] : 0.0f;
        float o[4];
#pragma unroll
        for (int jj = 0; jj < 4; ++jj) o[jj] = valid ? (acc[i][jj] + bias) : 0.0f;
        *(float4*)(drow + (size_t)j * 192 + tx * 4) = make_float4(o[0], o[1], o[2], o[3]);
    }
}

__global__ void k_pack(const float* __restrict__ qslab, const float* __restrict__ kslab,
                       short* __restrict__ qpack, short* __restrict__ kpack) {
    const int kstep = blockIdx.x, b = blockIdx.y, tensor = blockIdx.z;
    const float* src = (tensor ? kslab : qslab) + (size_t)b * (CPAD * 192);
    short* dst = (tensor ? kpack : qpack) + (size_t)(b * KSTEPS + kstep) * PACK_BK;
    const int t = threadIdx.x;
    const int tile = t >> 6, lane = t & 63;
    const int hf = (lane >> 5) & 1, col = lane & 31;
    const int dbase = kstep * 16 + hf * 8;
    const int x = tile * 32 + col;

    short8 H, L;
#pragma unroll
    for (int e = 0; e < 8; ++e) {
        float v = src[(size_t)(dbase + e) * 192 + x];
        unsigned short h = f2bf(v);
        unsigned short l = f2bf(v - bf2f(h));
        H[e] = (short)h;
        L[e] = (short)l;
    }
    ((short8*)dst)[(0 * 6 + tile) * 64 + lane] = H;
    ((short8*)dst)[(1 * 6 + tile) * 64 + lane] = L;
}

__global__ __launch_bounds__(256, 2)
void k_corr(const short* __restrict__ qpack, const short* __restrict__ kpack,
            const float* __restrict__ sig, float* __restrict__ sc) {
    __shared__ short smem[2 * 12288];
    const int qk = blockIdx.x, q = qk >> 5, k = qk & 31;
    const int tid = threadIdx.x, lane = tid & 63, w = tid >> 6;
    const int ws = w >> 1, wt = w & 1;
    const char* Abase = (const char*)(kpack + (size_t)k * KSTEPS * PACK_BK);
    const char* Bbase = (const char*)(qpack + (size_t)q * KSTEPS * PACK_BK);

    f32x16 acc[3][3];
#pragma unroll
    for (int i = 0; i < 3; ++i)
#pragma unroll
        for (int j = 0; j < 3; ++j)
#pragma unroll
            for (int r = 0; r < 16; ++r) acc[i][j][r] = 0.0f;

    auto stage = [&](int buf, int ks) {
#pragma unroll
        for (int u = 0; u < 6; ++u) {
            int c = u * 4 + w;
            const char* g = (c < 12 ? Abase + (size_t)ks * 12288 + c * 1024
                                    : Bbase + (size_t)ks * 12288 + (c - 12) * 1024) + lane * 16;
            g2lds16(g, (char*)smem + buf * 24576 + c * 1024);
        }
    };

    stage(0, 0);
    __syncthreads();

    int buf = 0;
    for (int ks = 0; ks < KSTEPS; ++ks) {
        if (ks + 1 < KSTEPS) stage(buf ^ 1, ks + 1);

        const short8* LA = (const short8*)((const char*)smem + buf * 24576);
        const short8* LB = (const short8*)((const char*)smem + buf * 24576 + 12288);
        short8 Ah[3], Al[3], Bh[3], Bl[3];
#pragma unroll
        for (int u = 0; u < 3; ++u) {
            Ah[u] = LA[(0 * 6 + ws * 3 + u) * 64 + lane];
            Al[u] = LA[(1 * 6 + ws * 3 + u) * 64 + lane];
            Bh[u] = LB[(0 * 6 + wt * 3 + u) * 64 + lane];
            Bl[u] = LB[(1 * 6 + wt * 3 + u) * 64 + lane];
        }
#pragma unroll
        for (int i = 0; i < 3; ++i)
#pragma unroll
            for (int j = 0; j < 3; ++j) {
                acc[i][j] = __builtin_amdgcn_mfma_f32_32x32x16_bf16(Ah[i], Bh[j], acc[i][j], 0, 0, 0);
                acc[i][j] = __builtin_amdgcn_mfma_f32_32x32x16_bf16(Al[i], Bh[j], acc[i][j], 0, 0, 0);
                acc[i][j] = __builtin_amdgcn_mfma_f32_32x32x16_bf16(Ah[i], Bl[j], acc[i][j], 0, 0, 0);
            }
        __syncthreads();
        buf ^= 1;
    }

    const int col = lane & 31, hf = lane >> 5;
    float* scr = (float*)smem;
    float cm[3] = {-3.0e38f, -3.0e38f, -3.0e38f};
#pragma unroll
    for (int i = 0; i < 3; ++i) {
        const int sbase = (ws * 3 + i) * 32;
        float rv[16];
#pragma unroll
        for (int r = 0; r < 16; ++r) rv[r] = -3.0e38f;
#pragma unroll
        for (int j = 0; j < 3; ++j) {
            const int tb = (wt * 3 + j) * 32 + col;
#pragma unroll
            for (int r = 0; r < 16; ++r) {
                int row = (r & 3) + 8 * (r >> 2) + 4 * hf;
                float v = acc[i][j][r] * sig[(size_t)(sbase + row) * 192 + tb];
                rv[r] = fmaxf(rv[r], v);
                cm[j] = fmaxf(cm[j], v);
            }
        }
#pragma unroll
        for (int m = 1; m < 32; m <<= 1)
#pragma unroll
            for (int r = 0; r < 16; ++r) rv[r] = fmaxf(rv[r], __shfl_xor(rv[r], m));
#pragma unroll
        for (int r = 0; r < 16; ++r)
            if (col == r)
                scr[384 + wt * 192 + sbase + (r & 3) + 8 * (r >> 2) + 4 * hf] = rv[r];
    }
#pragma unroll
    for (int j = 0; j < 3; ++j) {
        float c2 = fmaxf(cm[j], __shfl_xor(cm[j], 32));
        if (hf == 0) scr[ws * 192 + (wt * 3 + j) * 32 + col] = c2;
    }
    __syncthreads();
    if (tid < 192) {
        sc[(size_t)(2 * qk) * 192 + tid]     = fmaxf(scr[tid], scr[192 + tid]);
        sc[(size_t)(2 * qk + 1) * 192 + tid] = fmaxf(scr[384 + tid], scr[384 + 192 + tid]);
    }
}

__global__ __launch_bounds__(256, 2)
void k_fc2(const float* __restrict__ sc, const float* __restrict__ w2, float* __restrict__ out2) {
    __shared__ float Ast[32 * 132];
    __shared__ float Bst[32 * 132];
    const int bm = blockIdx.x & 15, bn = blockIdx.x >> 4;
    const int r0 = bm * 128, c0 = bn * 128;
    const int tid = threadIdx.x, ty = tid >> 4, tx = tid & 15;
    const int r = tid >> 1, half = (tid & 1) * 16;

    float acc[8][8];
#pragma unroll
    for (int i = 0; i < 8; ++i)
#pragma unroll
        for (int j = 0; j < 8; ++j) acc[i][j] = 0.0f;

    for (int t0 = 0; t0 < 192; t0 += 32) {
        float4 av[4], bv[4];
        const float4* ga = (const float4*)(sc + (size_t)(r0 + r) * 192 + t0 + half);
        const float4* gb = (const float4*)(w2 + (size_t)(c0 + r) * 192 + t0 + half);
#pragma unroll
        for (int e = 0; e < 4; ++e) { av[e] = ga[e]; bv[e] = gb[e]; }
        __syncthreads();
#pragma unroll
        for (int e = 0; e < 4; ++e) {
            int t = half + 4 * e;
            Ast[(t + 0) * 132 + r] = av[e].x;  Bst[(t + 0) * 132 + r] = bv[e].x;
            Ast[(t + 1) * 132 + r] = av[e].y;  Bst[(t + 1) * 132 + r] = bv[e].y;
            Ast[(t + 2) * 132 + r] = av[e].z;  Bst[(t + 2) * 132 + r] = bv[e].z;
            Ast[(t + 3) * 132 + r] = av[e].w;  Bst[(t + 3) * 132 + r] = bv[e].w;
        }
        __syncthreads();
#pragma unroll 4
        for (int kk = 0; kk < 32; ++kk) {
            const float4* ap = (const float4*)(Ast + kk * 132 + ty * 8);
            const float4* bp = (const float4*)(Bst + kk * 132 + tx * 8);
            float4 A0 = ap[0], A1 = ap[1];
            float4 B0 = bp[0], B1 = bp[1];
            float a[8] = {A0.x, A0.y, A0.z, A0.w, A1.x, A1.y, A1.z, A1.w};
            float b[8] = {B0.x, B0.y, B0.z, B0.w, B1.x, B1.y, B1.z, B1.w};
#pragma unroll
            for (int i = 0; i < 8; ++i)
#pragma unroll
                for (int j = 0; j < 8; ++j)
                    acc[i][j] = fmaf(a[i], b[j], acc[i][j]);
        }
    }
#pragma unroll
    for (int i = 0; i < 8; ++i) {
        float4* op = (float4*)(out2 + (size_t)(r0 + ty * 8 + i) * 2048 + c0 + tx * 8);
        op[0] = make_float4(acc[i][0], acc[i][1], acc[i][2], acc[i][3]);
        op[1] = make_float4(acc[i][4], acc[i][5], acc[i][6], acc[i][7]);
    }
}

__global__ void k_colp(const float* __restrict__ out2, float* __restrict__ colp) {
    const int bc = blockIdx.x & 7, br = blockIdx.x >> 3;
    const int j = bc * 256 + threadIdx.x;
    float s = 0.0f, s2 = 0.0f;
    for (int rr = br * 64; rr < br * 64 + 64; ++rr) {
        float vv = out2[(size_t)rr * 2048 + j];
        s += vv; s2 += vv * vv;
    }
    colp[((size_t)br * 2048 + j) * 2 + 0] = s;
    colp[((size_t)br * 2048 + j) * 2 + 1] = s2;
}

__global__ void k_colf(const float* __restrict__ colp, float* __restrict__ m2r2) {
    const int j = blockIdx.x * 256 + threadIdx.x;
    if (j >= 2048) return;
    float s = 0.0f, s2 = 0.0f;
    for (int br = 0; br < 32; ++br) {
        s  += colp[((size_t)br * 2048 + j) * 2 + 0];
        s2 += colp[((size_t)br * 2048 + j) * 2 + 1];
    }
    float m = s * (1.0f / 2048.0f);
    float var = s2 * (1.0f / 2048.0f) - m * m;
    m2r2[j * 2 + 0] = m;
    m2r2[j * 2 + 1] = rsqrtf(var + EPS);
}

__global__ void k_fc3(const float* __restrict__ out2, const float* __restrict__ m2r2,
                      const float* __restrict__ w3, float* __restrict__ y) {
    const int rr = blockIdx.x;
    const int tid = threadIdx.x;
    __shared__ float red[4];
    float s = 0.0f;
    for (int j = tid; j < 2048; j += 256) {
        float2 mr = ((const float2*)m2r2)[j];
        float vv = (out2[(size_t)rr * 2048 + j] - mr.x) * mr.y;
        vv = fmaxf(vv, 0.0f);
        s += vv * w3[j];
    }
#pragma unroll
    for (int off = 32; off; off >>= 1) s += __shfl_xor(s, off);
    if ((tid & 63) == 0) red[tid >> 6] = s;
    __syncthreads();
    if (tid == 0) y[rr] = red[0] + red[1] + red[2] + red[3];
}

__global__ void k_bn3(const float* __restrict__ y, float* __restrict__ score, int first) {
    const int tid = threadIdx.x;
    __shared__ float rs[4], rs2[4];
    float p[4]; float s = 0.0f, s2 = 0.0f;
#pragma unroll
    for (int u = 0; u < 4; ++u) {
        int i = tid + (u << 8);
        float vv = y[2 * i] + y[2 * i + 1];
        p[u] = vv; s += vv; s2 += vv * vv;
    }
#pragma unroll
    for (int off = 32; off; off >>= 1) { s += __shfl_xor(s, off); s2 += __shfl_xor(s2, off); }
    if ((tid & 63) == 0) { rs[tid >> 6] = s; rs2[tid >> 6] = s2; }
    __syncthreads();
    float S = rs[0] + rs[1] + rs[2] + rs[3];
    float S2 = rs2[0] + rs2[1] + rs2[2] + rs2[3];
    float m = S * (1.0f / 1024.0f);
    float var = S2 * (1.0f / 1024.0f) - m * m;
    float rstd = rsqrtf(var + EPS);
#pragma unroll
    for (int u = 0; u < 4; ++u) {
        int i = tid + (u << 8);
        float vv = (p[u] - m) * rstd;
        score[i] = first ? vv : (score[i] + vv);
    }
}

__global__ void k_final(const float* __restrict__ score, float* __restrict__ out) {
    const int tid = threadIdx.x;
    __shared__ float rs[4], rs2[4];
    float p[4]; float s = 0.0f, s2 = 0.0f;
#pragma unroll
    for (int u = 0; u < 4; ++u) {
        int i = tid + (u << 8);
        float vv = score[i];
        p[u] = vv; s += vv; s2 += vv * vv;
    }
#pragma unroll
    for (int off = 32; off; off >>= 1) { s += __shfl_xor(s, off); s2 += __shfl_xor(s2, off); }
    if ((tid & 63) == 0) { rs[tid >> 6] = s; rs2[tid >> 6] = s2; }
    __syncthreads();
    float S = rs[0] + rs[1] + rs[2] + rs[3];
    float S2 = rs2[0] + rs2[1] + rs2[2] + rs2[3];
    float m = S * (1.0f / 1024.0f);
    float var = S2 * (1.0f / 1024.0f) - m * m;
    float rstd = rsqrtf(var + EPS);
#pragma unroll
    for (int u = 0; u < 4; ++u) {
        int i = tid + (u << 8);
        out[i] = (p[u] - m) * rstd;
    }
}

// ---------------- launch ----------------
extern "C" void kernel_launch(void* const* d_in, const int* in_sizes, int n_in,
                              void* d_out, int out_size, void* d_ws, size_t ws_size,
                              hipStream_t stream) {
    const float* gallery = (const float*)d_in[0];
    const float* query   = (const float*)d_in[1];
    float* ws = (float*)d_ws;

    const bool batched = (ws_size >= (size_t)B_TOTAL * sizeof(float));

    if (batched) {
        short* scp = (short*)(ws + B_SCPF);
        short* w2p = (short*)(ws + B_W2PF);
        short* packs = (short*)(ws + B_PACKF);

        k_sigse<<<(3 * 36864 + 255) / 256, 256, 0, stream>>>(
            (const float*)d_in[2 + 0 * 7 + 2], (const float*)d_in[2 + 1 * 7 + 2],
            (const float*)d_in[2 + 2 * 7 + 2], ws + B_SIGSE);
        k_w1t_b<<<(3 * CPAD * MPAD + 255) / 256, 256, 0, stream>>>(
            (const float*)d_in[2 + 0 * 7 + 0], (const float*)d_in[2 + 1 * 7 + 0],
            (const float*)d_in[2 + 2 * 7 + 0], ws + B_W1T);
        k_fc1p_b<<<dim3(3, 32, 6), 256, 0, stream>>>(
            gallery, query, ws + B_W1T,
            (const float*)d_in[2 + 0 * 7 + 1], (const float*)d_in[2 + 1 * 7 + 1],
            (const float*)d_in[2 + 2 * 7 + 1], packs);
        k_w2p<<<dim3(64, 3), 256, 0, stream>>>(
            (const float*)d_in[2 + 0 * 7 + 3], (const float*)d_in[2 + 1 * 7 + 3],
            (const float*)d_in[2 + 2 * 7 + 3], w2p);
        k_corr_b<<<3072, 256, 0, stream>>>(packs, ws + B_SIGSE, scp);
        k_fc2m_b<<<dim3(256, 3), 256, 0, stream>>>(scp, w2p, ws + B_OUT2, ws + B_COLP);
        k_colf_b<<<24, 256, 0, stream>>>(ws + B_COLP, ws + B_M2R2);
        k_fc3_b<<<dim3(2048, 3), 256, 0, stream>>>(
            ws + B_OUT2, ws + B_M2R2,
            (const float*)d_in[2 + 0 * 7 + 5], (const float*)d_in[2 + 1 * 7 + 5],
            (const float*)d_in[2 + 2 * 7 + 5], ws + B_Y);
        k_bn3_b<<<3, 256, 0, stream>>>(ws + B_Y, ws + B_SC3);
        k_final3<<<1, 256, 0, stream>>>(ws + B_SC3, (float*)d_out);
        return;
    }

    // ---- fallback: proven per-layer pipeline (28.1 MB ws) ----
    const int cs[3] = {171, 171, 170};
    const int st[3] = {0, 171, 342};

    short* qpack = (short*)(ws + OFF_QPACK);
    short* kpack = (short*)(ws + OFF_KPACK);

    k_sigse<<<(3 * 36864 + 255) / 256, 256, 0, stream>>>(
        (const float*)d_in[2 + 0 * 7 + 2], (const float*)d_in[2 + 1 * 7 + 2],
        (const float*)d_in[2 + 2 * 7 + 2], ws + OFF_SIGSE);

    for (int l = 0; l < 3; ++l) {
        const float* w1 = (const float*)d_in[2 + l * 7 + 0];
        const float* b1 = (const float*)d_in[2 + l * 7 + 1];
        const float* w2 = (const float*)d_in[2 + l * 7 + 3];
        const float* w3 = (const float*)d_in[2 + l * 7 + 5];

        k_w1t<<<(CPAD * CPAD + 255) / 256, 256, 0, stream>>>(w1, cs[l], ws + OFF_W1T);
        k_fc1<<<dim3(3, 32, 2), 256, 0, stream>>>(gallery, query, ws + OFF_W1T, b1,
                                                  cs[l], st[l], ws + OFF_QSLAB, ws + OFF_KSLAB);
        k_pack<<<dim3(KSTEPS, 32, 2), 384, 0, stream>>>(ws + OFF_QSLAB, ws + OFF_KSLAB,
                                                        qpack, kpack);
        k_corr<<<1024, 256, 0, stream>>>(qpack, kpack, ws + OFF_SIGSE + l * 36864, ws + OFF_SC);
        k_fc2<<<256, 256, 0, stream>>>(ws + OFF_SC, w2, ws + OFF_OUT2);
        k_colp<<<256, 256, 0, stream>>>(ws + OFF_OUT2, ws + OFF_COLP);
        k_colf<<<8, 256, 0, stream>>>(ws + OFF_COLP, ws + OFF_M2V2);
        k_fc3<<<2048, 256, 0, stream>>>(ws + OFF_OUT2, ws + OFF_M2V2, w3, ws + OFF_Y);
        k_bn3<<<1, 256, 0, stream>>>(ws + OFF_Y, ws + OFF_SCORE, l == 0 ? 1 : 0);
    }
    k_final<<<1, 256, 0, stream>>>(ws + OFF_SCORE, (float*)d_out);
}